// Round 6
// baseline (2053.163 us; speedup 1.0000x reference)
//
#include <hip/hip_runtime.h>

#define NN 50000
#define NE 1600000
#define DD 128
#define NL 4
#define NG 512
#define BSH 7       // bucket shift: 128 nodes per bucket
#define BMSK 127
#define NBUK 391    // ceil(50000/128)
#define NBLK 896    // edge partitions == K1 grid
#define EPB 1786    // ceil(NE/NBLK)
#define HN (NBUK * NBLK)  // 350336; note HN/NBLK == NBUK (exact chunks)
#define EPT 20      // bucket_csr: max edges per thread (seg mean 4096, max ~4350; cap 5120)
#define G1 896      // K1 grid (cap 4 blocks/CU * 256 = 1024)
#define G2 704      // K2 grid (cap 3 blocks/CU * 256 = 768)
#define CVT_N (NN * DD / 4)    // 1600000
#define PREP_N (NL * DD * DD)  // 65536
#define NCH 3125    // agg chunks of 16 nodes
#define NT2 782     // mlp 64-row tiles

typedef __attribute__((ext_vector_type(8))) short short8;
typedef __attribute__((ext_vector_type(4))) float floatx4;

__device__ __forceinline__ unsigned short f2bf(float f) {
    unsigned int u = __float_as_uint(f);
    u += 0x7fffu + ((u >> 16) & 1u);
    return (unsigned short)(u >> 16);
}
__device__ __forceinline__ float bf2f(unsigned short u) {
    return __uint_as_float(((unsigned int)u) << 16);
}

// Device-wide barrier: one arrival per block on an agent-scope counter.
// Counter zeroed per graph-replay by a captured hipMemsetAsync (never reset
// in-kernel: resetting races blocks still spinning on the previous epoch).
// Release on arrive publishes this block's writes (L2 writeback); acquire on
// the spin + __syncthreads makes peers' writes visible (L1/L2 invalidate).
__device__ __forceinline__ void grid_barrier(unsigned int* c, unsigned int target) {
    __syncthreads();
    if (threadIdx.x == 0) {
        __hip_atomic_fetch_add(c, 1u, __ATOMIC_RELEASE, __HIP_MEMORY_SCOPE_AGENT);
        while (__hip_atomic_load(c, __ATOMIC_ACQUIRE, __HIP_MEMORY_SCOPE_AGENT) < target)
            __builtin_amdgcn_s_sleep(2);
    }
    __syncthreads();
}

// ================= K1: cvt + weight prep + full CSR build, 1 dispatch =======
// R5(this session): dispatch-overhead is the sink (~8us x 17 nodes). All CSR
// passes become phases of one persistent kernel with grid barriers.
__global__ __launch_bounds__(256, 4) void build_kernel(
    const float* __restrict__ x0, const int* __restrict__ edge,
    unsigned short* __restrict__ x0bf,
    const float* __restrict__ Ws1, const float* __restrict__ Ws2,
    unsigned short* __restrict__ W1T, unsigned short* __restrict__ W2T,
    int* __restrict__ hist, int* __restrict__ tsum, int* __restrict__ toff,
    int* __restrict__ bkoff, int* __restrict__ ebuf,
    int* __restrict__ rowptr, int* __restrict__ rowend, int* __restrict__ col,
    unsigned int* __restrict__ syncm) {
    __shared__ int sh[400];
    const int tid = threadIdx.x, bid = blockIdx.x;
    const int gid = bid * 256 + tid;
    const int* src = edge;
    const int* dst = edge + NE;
    unsigned int tgt = 0;

    // ---- P0: fp32->bf16 cvt, weight transpose, per-partition bucket hist ----
    for (int idx = gid; idx < CVT_N; idx += G1 * 256) {
        float4 f = ((const float4*)x0)[idx];
        ushort4 o;
        o.x = f2bf(f.x); o.y = f2bf(f.y); o.z = f2bf(f.z); o.w = f2bf(f.w);
        ((ushort4*)x0bf)[idx] = o;
    }
    for (int idx = gid; idx < PREP_N; idx += G1 * 256) {
        int l = idx >> 14, rem = idx & 16383;
        int k = rem >> 7, n = rem & 127;
        int o = (l << 14) + (n << 7) + k;
        W1T[o] = f2bf(Ws1[idx]);
        W2T[o] = f2bf(Ws2[idx]);
    }
    for (int i = tid; i < NBUK; i += 256) sh[i] = 0;
    __syncthreads();
    {
        int base = bid * EPB;
        int end = base + EPB; if (end > NE) end = NE;
        for (int e = base + tid; e < end; e += 256) atomicAdd(&sh[dst[e] >> BSH], 1);
    }
    __syncthreads();
    for (int i = tid; i < NBUK; i += 256) hist[i * NBLK + bid] = sh[i];
    tgt += G1; grid_barrier(syncm, tgt);

    // ---- P1: per-chunk sums (chunk = NBUK contiguous els, one per block) ----
    {
        int base = bid * NBUK;
        int acc = 0;
        for (int i = tid; i < NBUK; i += 256) acc += hist[base + i];
        sh[tid] = acc;
        __syncthreads();
        for (int off = 128; off > 0; off >>= 1) {
            if (tid < off) sh[tid] += sh[tid + off];
            __syncthreads();
        }
        if (tid == 0) tsum[bid] = sh[0];
    }
    tgt += G1; grid_barrier(syncm, tgt);

    // ---- P2: block 0 exclusive-scans tsum[896] -> toff[896] (4 els/thread) ----
    if (bid == 0) {
        int a0 = 0, a1 = 0, a2 = 0, a3 = 0, p = 0;
        if (tid < 224) {
            a0 = tsum[4 * tid]; a1 = tsum[4 * tid + 1];
            a2 = tsum[4 * tid + 2]; a3 = tsum[4 * tid + 3];
            p = a0 + a1 + a2 + a3;
        }
        sh[tid] = p;
        __syncthreads();
        for (int off = 1; off < 256; off <<= 1) {
            int u = (tid >= off) ? sh[tid - off] : 0;
            __syncthreads();
            sh[tid] += u;
            __syncthreads();
        }
        if (tid < 224) {
            int ex = sh[tid] - p;
            toff[4 * tid] = ex; ex += a0;
            toff[4 * tid + 1] = ex; ex += a1;
            toff[4 * tid + 2] = ex; ex += a2;
            toff[4 * tid + 3] = ex;
        }
    }
    tgt += G1; grid_barrier(syncm, tgt);

    // ---- P3: per-chunk exclusive prefix + toff -> bkoff (2 els/thread) ----
    {
        int base = bid * NBUK;
        int a0 = (2 * tid < NBUK) ? hist[base + 2 * tid] : 0;
        int a1 = (2 * tid + 1 < NBUK) ? hist[base + 2 * tid + 1] : 0;
        int p = a0 + a1;
        sh[tid] = p;
        __syncthreads();
        for (int off = 1; off < 256; off <<= 1) {
            int u = (tid >= off) ? sh[tid - off] : 0;
            __syncthreads();
            sh[tid] += u;
            __syncthreads();
        }
        int ex = sh[tid] - p + toff[bid];
        if (2 * tid < NBUK) bkoff[base + 2 * tid] = ex;
        if (2 * tid + 1 < NBUK) bkoff[base + 2 * tid + 1] = ex + a0;
    }
    tgt += G1; grid_barrier(syncm, tgt);

    // ---- P4: scatter edges into bucket-sorted ebuf, packed (src<<7)|(dst&127) ----
    for (int i = tid; i < NBUK; i += 256) sh[i] = 0;
    __syncthreads();
    {
        int base = bid * EPB;
        int end = base + EPB; if (end > NE) end = NE;
        for (int e = base + tid; e < end; e += 256) {
            int d = dst[e];
            int bu = d >> BSH;
            int p = atomicAdd(&sh[bu], 1);
            ebuf[bkoff[bu * NBLK + bid] + p] = (src[e] << BSH) | (d & BMSK);
        }
    }
    tgt += G1; grid_barrier(syncm, tgt);

    // ---- P5: per-bucket CSR finalize (single segment read, reg-held) ----
    if (bid < NBUK) {
        int* cnt = sh; int* exc = sh + 128; int* ebase = sh + 256;
        int b = bid;
        int segstart = bkoff[b * NBLK];
        int segend = (b < NBUK - 1) ? bkoff[(b + 1) * NBLK] : NE;
        if (tid < 128) cnt[tid] = 0;
        __syncthreads();
        int evr[EPT], rnk[EPT];
#pragma unroll
        for (int j = 0; j < EPT; j++) {
            int i = segstart + tid + j * 256;
            if (i < segend) {
                int ev = ebuf[i];
                evr[j] = ev;
                rnk[j] = atomicAdd(&cnt[ev & BMSK], 1);
            } else {
                evr[j] = -1;
            }
        }
        __syncthreads();
        int v = (tid < 128) ? cnt[tid] : 0;
        if (tid < 128) exc[tid] = v;
        __syncthreads();
        for (int off = 1; off < 128; off <<= 1) {
            int u = (tid < 128 && tid >= off) ? exc[tid - off] : 0;
            __syncthreads();
            if (tid < 128) exc[tid] += u;
            __syncthreads();
        }
        if (tid < 128) {
            int excl = exc[tid] - v;
            ebase[tid] = segstart + excl;
            int node = (b << BSH) + tid;
            if (node < NN) {
                rowptr[node] = segstart + excl;
                rowend[node] = segstart + excl + v;
            }
        }
        __syncthreads();
#pragma unroll
        for (int j = 0; j < EPT; j++) {
            if (evr[j] >= 0) {
                int low = evr[j] & BMSK;
                col[ebase[low] + rnk[j]] = ((unsigned)evr[j]) >> BSH;
            }
        }
    }
}

// ================= K2: 4 x (agg -> mlp) + pool, 1 dispatch ==================
// 48KB LDS -> 3 blocks/CU (12 waves/CU). agg compensates occupancy with
// x16-deep gather batches (in-flight/CU >= R1's dispatch config; R2 showed
// perf is flat in total in-flight above ~128/CU). Dynamic per-layer chunk
// counter (prefetched under the body) avoids static-split imbalance.
__global__ __launch_bounds__(256, 3) void layers_kernel(
    const unsigned short* __restrict__ x0bf,
    unsigned short* __restrict__ xA, unsigned short* __restrict__ xB,
    unsigned short* __restrict__ hpre,
    const int* __restrict__ rowptr, const int* __restrict__ rowend,
    const int* __restrict__ col,
    const unsigned short* __restrict__ W1T, const unsigned short* __restrict__ W2T,
    const float* __restrict__ bs1, const float* __restrict__ bs2,
    const int* __restrict__ batch, float* __restrict__ out,
    unsigned int* __restrict__ syncm) {
    __shared__ unsigned short Wl[128 * 128];  // 32 KB: W1 then W2
    __shared__ unsigned short Hl[64 * 128];   // 16 KB: hidden tile / agg scratch / pool red
    const int tid = threadIdx.x, bid = blockIdx.x;
    unsigned int tgt = 0;
    int* wctr = (int*)(syncm + 2);  // 4 per-layer work counters (memset'd per replay)
    const unsigned short* xin = x0bf;

    for (int l = 0; l < NL; l++) {
        // ---------------- agg phase: hpre = x + sum_neighbors(x) ----------------
        {
            int* s_next = (int*)Hl;  // Hl unused during agg
            int g = tid >> 4, lane = tid & 15;
            const uint4* base = (const uint4*)xin;
            if (tid == 0) *s_next = atomicAdd(&wctr[l], 1);
            __syncthreads();
            int gidx = *s_next;
            while (gidx < NCH) {
                __syncthreads();
                if (tid == 0) *s_next = atomicAdd(&wctr[l], 1);  // prefetch next chunk
                int node = gidx * 16 + g;
                float a[8];
#define ACC(V)                                                                          \
                a[0] += __uint_as_float(V.x << 16); a[1] += __uint_as_float(V.x & 0xFFFF0000u); \
                a[2] += __uint_as_float(V.y << 16); a[3] += __uint_as_float(V.y & 0xFFFF0000u); \
                a[4] += __uint_as_float(V.z << 16); a[5] += __uint_as_float(V.z & 0xFFFF0000u); \
                a[6] += __uint_as_float(V.w << 16); a[7] += __uint_as_float(V.w & 0xFFFF0000u)
                {
                    uint4 v = base[node * 16 + lane];
                    a[0] = __uint_as_float(v.x << 16); a[1] = __uint_as_float(v.x & 0xFFFF0000u);
                    a[2] = __uint_as_float(v.y << 16); a[3] = __uint_as_float(v.y & 0xFFFF0000u);
                    a[4] = __uint_as_float(v.z << 16); a[5] = __uint_as_float(v.z & 0xFFFF0000u);
                    a[6] = __uint_as_float(v.w << 16); a[7] = __uint_as_float(v.w & 0xFFFF0000u);
                }
                int s = rowptr[node], e = rowend[node];
                int i = s;
                for (; i + 16 <= e; i += 16) {
                    uint4 v[16];
#pragma unroll
                    for (int u = 0; u < 16; u++) v[u] = base[col[i + u] * 16 + lane];
#pragma unroll
                    for (int u = 0; u < 16; u++) { ACC(v[u]); }
                }
                for (; i + 8 <= e; i += 8) {
                    uint4 v[8];
#pragma unroll
                    for (int u = 0; u < 8; u++) v[u] = base[col[i + u] * 16 + lane];
#pragma unroll
                    for (int u = 0; u < 8; u++) { ACC(v[u]); }
                }
                for (; i < e; i++) {
                    uint4 v = base[col[i] * 16 + lane];
                    ACC(v);
                }
#undef ACC
                uint4 o;
                o.x = (unsigned int)f2bf(a[0]) | ((unsigned int)f2bf(a[1]) << 16);
                o.y = (unsigned int)f2bf(a[2]) | ((unsigned int)f2bf(a[3]) << 16);
                o.z = (unsigned int)f2bf(a[4]) | ((unsigned int)f2bf(a[5]) << 16);
                o.w = (unsigned int)f2bf(a[6]) | ((unsigned int)f2bf(a[7]) << 16);
                ((uint4*)hpre)[node * 16 + lane] = o;
                __syncthreads();
                gidx = *s_next;
            }
        }
        tgt += G2; grid_barrier(&syncm[1], tgt);

        // ---------------- mlp phase: xout = (relu(hpre@W1^T+b1))@W2^T + b2 ------
        unsigned short* xout = (l & 1) ? xB : xA;
        const unsigned short* W1 = W1T + (l << 14);
        const unsigned short* W2 = W2T + (l << 14);
        const float* b1 = bs1 + l * DD;
        const float* b2 = bs2 + l * DD;
        for (int t = bid; t < NT2; t += G2) {
            int wg = tid >> 6;
            int lane = tid & 63;
            int quad = lane >> 4;
            int li = lane & 15;
            int mg = wg >> 1, ng = wg & 1;  // wave = 32 rows x 64 cols
            int rowb = t * 64;

            {
                const uint4* wgl = (const uint4*)W1;
#pragma unroll
                for (int it = 0; it < 8; it++) {
                    int idx = it * 256 + tid;
                    int n = idx >> 4, kc = idx & 15;
                    *(uint4*)&Wl[n * 128 + ((kc * 8) ^ ((n & 7) << 3))] = wgl[idx];
                }
            }
            __syncthreads();

            floatx4 acc[4][2];
#pragma unroll
            for (int tn = 0; tn < 4; tn++)
#pragma unroll
                for (int mi = 0; mi < 2; mi++) acc[tn][mi] = (floatx4){0.f, 0.f, 0.f, 0.f};

#pragma unroll
            for (int kk = 0; kk < 4; kk++) {
                int kc = kk * 32 + quad * 8;
                short8 xf[2];
#pragma unroll
                for (int mi = 0; mi < 2; mi++) {
                    int ar = rowb + mg * 32 + mi * 16 + li;
                    xf[mi] = (ar < NN) ? *(const short8*)(hpre + (size_t)ar * DD + kc)
                                       : (short8){0, 0, 0, 0, 0, 0, 0, 0};
                }
#pragma unroll
                for (int tn = 0; tn < 4; tn++) {
                    int wr = ng * 64 + tn * 16 + li;
                    short8 wf = *(const short8*)&Wl[wr * 128 + (kc ^ ((wr & 7) << 3))];
#pragma unroll
                    for (int mi = 0; mi < 2; mi++)
                        acc[tn][mi] = __builtin_amdgcn_mfma_f32_16x16x32_bf16(wf, xf[mi], acc[tn][mi], 0, 0, 0);
                }
            }

#pragma unroll
            for (int tn = 0; tn < 4; tn++) {
                float4 bv = ((const float4*)b1)[ng * 16 + tn * 4 + quad];
#pragma unroll
                for (int mi = 0; mi < 2; mi++) {
                    int hr = mg * 32 + mi * 16 + li;
                    float v0 = fmaxf(acc[tn][mi][0] + bv.x, 0.f);
                    float v1 = fmaxf(acc[tn][mi][1] + bv.y, 0.f);
                    float v2 = fmaxf(acc[tn][mi][2] + bv.z, 0.f);
                    float v3 = fmaxf(acc[tn][mi][3] + bv.w, 0.f);
                    uint2 u;
                    u.x = (unsigned int)f2bf(v0) | ((unsigned int)f2bf(v1) << 16);
                    u.y = (unsigned int)f2bf(v2) | ((unsigned int)f2bf(v3) << 16);
                    int c = (ng * 64 + tn * 16 + quad * 4) ^ ((hr & 7) << 3);
                    *(uint2*)&Hl[hr * 128 + c] = u;
                }
            }
            __syncthreads();

            {
                const uint4* wgl = (const uint4*)W2;
#pragma unroll
                for (int it = 0; it < 8; it++) {
                    int idx = it * 256 + tid;
                    int n = idx >> 4, kc = idx & 15;
                    *(uint4*)&Wl[n * 128 + ((kc * 8) ^ ((n & 7) << 3))] = wgl[idx];
                }
            }
            __syncthreads();

#pragma unroll
            for (int tn = 0; tn < 4; tn++)
#pragma unroll
                for (int mi = 0; mi < 2; mi++) acc[tn][mi] = (floatx4){0.f, 0.f, 0.f, 0.f};

#pragma unroll
            for (int kk = 0; kk < 4; kk++) {
                int kc = kk * 32 + quad * 8;
                short8 hf[2];
#pragma unroll
                for (int mi = 0; mi < 2; mi++) {
                    int hr = mg * 32 + mi * 16 + li;
                    hf[mi] = *(const short8*)&Hl[hr * 128 + (kc ^ ((hr & 7) << 3))];
                }
#pragma unroll
                for (int tn = 0; tn < 4; tn++) {
                    int wr = ng * 64 + tn * 16 + li;
                    short8 wf = *(const short8*)&Wl[wr * 128 + (kc ^ ((wr & 7) << 3))];
#pragma unroll
                    for (int mi = 0; mi < 2; mi++)
                        acc[tn][mi] = __builtin_amdgcn_mfma_f32_16x16x32_bf16(wf, hf[mi], acc[tn][mi], 0, 0, 0);
                }
            }

#pragma unroll
            for (int tn = 0; tn < 4; tn++) {
                float4 bv = ((const float4*)b2)[ng * 16 + tn * 4 + quad];
#pragma unroll
                for (int mi = 0; mi < 2; mi++) {
                    int m = rowb + mg * 32 + mi * 16 + li;
                    if (m < NN) {
                        uint2 u;
                        u.x = (unsigned int)f2bf(acc[tn][mi][0] + bv.x) |
                              ((unsigned int)f2bf(acc[tn][mi][1] + bv.y) << 16);
                        u.y = (unsigned int)f2bf(acc[tn][mi][2] + bv.z) |
                              ((unsigned int)f2bf(acc[tn][mi][3] + bv.w) << 16);
                        *(uint2*)&xout[(size_t)m * DD + ng * 64 + tn * 16 + quad * 4] = u;
                    }
                }
            }
            __syncthreads();  // protect Wl/Hl reuse on 2nd tile iteration
        }
        tgt += G2; grid_barrier(&syncm[1], tgt);
        xin = xout;
    }

    // ---------------- pool: per-graph add over sorted batch ranges ----------
    if (bid < NG) {
        int gph = bid;
        int lo = 0, hi = NN;
        while (lo < hi) { int mid = (lo + hi) >> 1; if (batch[mid] < gph) lo = mid + 1; else hi = mid; }
        int s = lo;
        hi = NN;
        while (lo < hi) { int mid = (lo + hi) >> 1; if (batch[mid] < gph + 1) lo = mid + 1; else hi = mid; }
        int e = lo;
        int d = tid & 127, half = tid >> 7;
        float acc = 0.f;
        for (int i = s + half; i < e; i += 2) acc += bf2f(xin[(size_t)i * DD + d]);
        float* red = (float*)Hl;
        red[tid] = acc;
        __syncthreads();
        if (tid < 128) out[gph * DD + d] = red[d] + red[128 + d];
    }
}

extern "C" void kernel_launch(void* const* d_in, const int* in_sizes, int n_in,
                              void* d_out, int out_size, void* d_ws, size_t ws_size,
                              hipStream_t stream) {
    const float* x0 = (const float*)d_in[0];
    const int* edge = (const int*)d_in[1];
    const int* batch = (const int*)d_in[2];
    const float* Ws1 = (const float*)d_in[3];
    const float* bs1 = (const float*)d_in[4];
    const float* Ws2 = (const float*)d_in[5];
    const float* bs2 = (const float*)d_in[6];
    float* out = (float*)d_out;

    char* ws = (char*)d_ws;
    size_t off = 0;
    auto alloc = [&](size_t bytes) {
        void* p = ws + off;
        off += (bytes + 255) & ~(size_t)255;
        return p;
    };
    unsigned short* x0bf = (unsigned short*)alloc((size_t)NN * DD * 2);
    unsigned short* xA = (unsigned short*)alloc((size_t)NN * DD * 2);
    unsigned short* xB = (unsigned short*)alloc((size_t)NN * DD * 2);
    unsigned short* hpre = (unsigned short*)alloc((size_t)NN * DD * 2);
    int* col = (int*)alloc((size_t)NE * 4);
    int* ebuf = (int*)alloc((size_t)NE * 4);
    int* hist = (int*)alloc((size_t)HN * 4);
    int* bkoff = (int*)alloc((size_t)HN * 4);
    int* tsum = (int*)alloc((size_t)NBLK * 4);
    int* toff = (int*)alloc((size_t)NBLK * 4);
    int* rowptr = (int*)alloc((size_t)(NN + 1) * 4);
    int* rowend = (int*)alloc((size_t)NN * 4);
    unsigned short* W1T = (unsigned short*)alloc((size_t)NL * DD * DD * 2);
    unsigned short* W2T = (unsigned short*)alloc((size_t)NL * DD * DD * 2);
    unsigned int* syncm = (unsigned int*)alloc(256);

    (void)hipMemsetAsync(syncm, 0, 256, stream);
    build_kernel<<<G1, 256, 0, stream>>>(x0, edge, x0bf, Ws1, Ws2, W1T, W2T,
                                         hist, tsum, toff, bkoff, ebuf,
                                         rowptr, rowend, col, syncm);
    layers_kernel<<<G2, 256, 0, stream>>>(x0bf, xA, xB, hpre, rowptr, rowend, col,
                                          W1T, W2T, bs1, bs2, batch, out, syncm);
}

// Round 8
// 1433.055 us; speedup vs baseline: 1.4327x; 1.4327x over previous
//
#include <hip/hip_runtime.h>

#define NN 50000
#define NE 1600000
#define DD 128
#define NL 4
#define NG 512
#define BSH 7       // bucket shift: 128 nodes per bucket
#define BMSK 127
#define NBUK 391    // ceil(50000/128)
#define NBLK 896    // edge partitions == K1 grid
#define EPB 1786    // ceil(NE/NBLK)
#define HN (NBUK * NBLK)  // 350336; note HN/NBLK == NBUK (exact chunks)
#define EPT 20      // bucket_csr: max edges per thread (seg mean 4096, max ~4350; cap 5120)
#define G1 896      // K1 grid (cap 4 blocks/CU * 256 = 1024)
#define G2 704      // K2 grid (cap 3 blocks/CU * 256 = 768)
#define CVT_N (NN * DD / 4)    // 1600000
#define PREP_N (NL * DD * DD)  // 65536
#define NCH 3125    // agg chunks of 16 nodes
#define NT2 782     // mlp 64-row tiles

typedef __attribute__((ext_vector_type(8))) short short8;
typedef __attribute__((ext_vector_type(4))) float floatx4;

__device__ __forceinline__ unsigned short f2bf(float f) {
    unsigned int u = __float_as_uint(f);
    u += 0x7fffu + ((u >> 16) & 1u);
    return (unsigned short)(u >> 16);
}
__device__ __forceinline__ float bf2f(unsigned short u) {
    return __uint_as_float(((unsigned int)u) << 16);
}

// Device-wide barrier, R7 fix: R6 spun on ACQUIRE loads — on gfx950 every
// agent-scope acquire emits a cache invalidate (software cross-XCD coherence),
// so 700+ spinning blocks invalidated L1/L2 continuously while others worked:
// uniform ~6x slowdown, FETCH unchanged (L3 absorbed re-reads). Fix: RELAXED
// spin (no cache side effects; still bypasses L2 per agent-scope policy, so
// remote fetch_adds are observed) + ONE acquire load after the spin breaks
// (one invalidate per block per barrier), before __syncthreads releases
// consumers.
__device__ __forceinline__ void grid_barrier(unsigned int* c, unsigned int target) {
    __syncthreads();
    if (threadIdx.x == 0) {
        __hip_atomic_fetch_add(c, 1u, __ATOMIC_RELEASE, __HIP_MEMORY_SCOPE_AGENT);
        while (__hip_atomic_load(c, __ATOMIC_RELAXED, __HIP_MEMORY_SCOPE_AGENT) < target)
            __builtin_amdgcn_s_sleep(8);
        (void)__hip_atomic_load(c, __ATOMIC_ACQUIRE, __HIP_MEMORY_SCOPE_AGENT);
    }
    __syncthreads();
}

// ================= K1: cvt + weight prep + full CSR build, 1 dispatch =======
// R5(this session): dispatch-overhead is the sink (~8us x 17 nodes). All CSR
// passes become phases of one persistent kernel with grid barriers.
__global__ __launch_bounds__(256, 4) void build_kernel(
    const float* __restrict__ x0, const int* __restrict__ edge,
    unsigned short* __restrict__ x0bf,
    const float* __restrict__ Ws1, const float* __restrict__ Ws2,
    unsigned short* __restrict__ W1T, unsigned short* __restrict__ W2T,
    int* __restrict__ hist, int* __restrict__ tsum, int* __restrict__ toff,
    int* __restrict__ bkoff, int* __restrict__ ebuf,
    int* __restrict__ rowptr, int* __restrict__ rowend, int* __restrict__ col,
    unsigned int* __restrict__ syncm) {
    __shared__ int sh[400];
    const int tid = threadIdx.x, bid = blockIdx.x;
    const int gid = bid * 256 + tid;
    const int* src = edge;
    const int* dst = edge + NE;
    unsigned int tgt = 0;

    // ---- P0: fp32->bf16 cvt, weight transpose, per-partition bucket hist ----
    for (int idx = gid; idx < CVT_N; idx += G1 * 256) {
        float4 f = ((const float4*)x0)[idx];
        ushort4 o;
        o.x = f2bf(f.x); o.y = f2bf(f.y); o.z = f2bf(f.z); o.w = f2bf(f.w);
        ((ushort4*)x0bf)[idx] = o;
    }
    for (int idx = gid; idx < PREP_N; idx += G1 * 256) {
        int l = idx >> 14, rem = idx & 16383;
        int k = rem >> 7, n = rem & 127;
        int o = (l << 14) + (n << 7) + k;
        W1T[o] = f2bf(Ws1[idx]);
        W2T[o] = f2bf(Ws2[idx]);
    }
    for (int i = tid; i < NBUK; i += 256) sh[i] = 0;
    __syncthreads();
    {
        int base = bid * EPB;
        int end = base + EPB; if (end > NE) end = NE;
        for (int e = base + tid; e < end; e += 256) atomicAdd(&sh[dst[e] >> BSH], 1);
    }
    __syncthreads();
    for (int i = tid; i < NBUK; i += 256) hist[i * NBLK + bid] = sh[i];
    tgt += G1; grid_barrier(syncm, tgt);

    // ---- P1: per-chunk sums (chunk = NBUK contiguous els, one per block) ----
    {
        int base = bid * NBUK;
        int acc = 0;
        for (int i = tid; i < NBUK; i += 256) acc += hist[base + i];
        sh[tid] = acc;
        __syncthreads();
        for (int off = 128; off > 0; off >>= 1) {
            if (tid < off) sh[tid] += sh[tid + off];
            __syncthreads();
        }
        if (tid == 0) tsum[bid] = sh[0];
    }
    tgt += G1; grid_barrier(syncm, tgt);

    // ---- P2: block 0 exclusive-scans tsum[896] -> toff[896] (4 els/thread) ----
    if (bid == 0) {
        int a0 = 0, a1 = 0, a2 = 0, a3 = 0, p = 0;
        if (tid < 224) {
            a0 = tsum[4 * tid]; a1 = tsum[4 * tid + 1];
            a2 = tsum[4 * tid + 2]; a3 = tsum[4 * tid + 3];
            p = a0 + a1 + a2 + a3;
        }
        sh[tid] = p;
        __syncthreads();
        for (int off = 1; off < 256; off <<= 1) {
            int u = (tid >= off) ? sh[tid - off] : 0;
            __syncthreads();
            sh[tid] += u;
            __syncthreads();
        }
        if (tid < 224) {
            int ex = sh[tid] - p;
            toff[4 * tid] = ex; ex += a0;
            toff[4 * tid + 1] = ex; ex += a1;
            toff[4 * tid + 2] = ex; ex += a2;
            toff[4 * tid + 3] = ex;
        }
    }
    tgt += G1; grid_barrier(syncm, tgt);

    // ---- P3: per-chunk exclusive prefix + toff -> bkoff (2 els/thread) ----
    {
        int base = bid * NBUK;
        int a0 = (2 * tid < NBUK) ? hist[base + 2 * tid] : 0;
        int a1 = (2 * tid + 1 < NBUK) ? hist[base + 2 * tid + 1] : 0;
        int p = a0 + a1;
        sh[tid] = p;
        __syncthreads();
        for (int off = 1; off < 256; off <<= 1) {
            int u = (tid >= off) ? sh[tid - off] : 0;
            __syncthreads();
            sh[tid] += u;
            __syncthreads();
        }
        int ex = sh[tid] - p + toff[bid];
        if (2 * tid < NBUK) bkoff[base + 2 * tid] = ex;
        if (2 * tid + 1 < NBUK) bkoff[base + 2 * tid + 1] = ex + a0;
    }
    tgt += G1; grid_barrier(syncm, tgt);

    // ---- P4: scatter edges into bucket-sorted ebuf, packed (src<<7)|(dst&127) ----
    for (int i = tid; i < NBUK; i += 256) sh[i] = 0;
    __syncthreads();
    {
        int base = bid * EPB;
        int end = base + EPB; if (end > NE) end = NE;
        for (int e = base + tid; e < end; e += 256) {
            int d = dst[e];
            int bu = d >> BSH;
            int p = atomicAdd(&sh[bu], 1);
            ebuf[bkoff[bu * NBLK + bid] + p] = (src[e] << BSH) | (d & BMSK);
        }
    }
    tgt += G1; grid_barrier(syncm, tgt);

    // ---- P5: per-bucket CSR finalize (single segment read, reg-held) ----
    if (bid < NBUK) {
        int* cnt = sh; int* exc = sh + 128; int* ebase = sh + 256;
        int b = bid;
        int segstart = bkoff[b * NBLK];
        int segend = (b < NBUK - 1) ? bkoff[(b + 1) * NBLK] : NE;
        if (tid < 128) cnt[tid] = 0;
        __syncthreads();
        int evr[EPT], rnk[EPT];
#pragma unroll
        for (int j = 0; j < EPT; j++) {
            int i = segstart + tid + j * 256;
            if (i < segend) {
                int ev = ebuf[i];
                evr[j] = ev;
                rnk[j] = atomicAdd(&cnt[ev & BMSK], 1);
            } else {
                evr[j] = -1;
            }
        }
        __syncthreads();
        int v = (tid < 128) ? cnt[tid] : 0;
        if (tid < 128) exc[tid] = v;
        __syncthreads();
        for (int off = 1; off < 128; off <<= 1) {
            int u = (tid < 128 && tid >= off) ? exc[tid - off] : 0;
            __syncthreads();
            if (tid < 128) exc[tid] += u;
            __syncthreads();
        }
        if (tid < 128) {
            int excl = exc[tid] - v;
            ebase[tid] = segstart + excl;
            int node = (b << BSH) + tid;
            if (node < NN) {
                rowptr[node] = segstart + excl;
                rowend[node] = segstart + excl + v;
            }
        }
        __syncthreads();
#pragma unroll
        for (int j = 0; j < EPT; j++) {
            if (evr[j] >= 0) {
                int low = evr[j] & BMSK;
                col[ebase[low] + rnk[j]] = ((unsigned)evr[j]) >> BSH;
            }
        }
    }
}

// ================= K2: 4 x (agg -> mlp) + pool, 1 dispatch ==================
// 48KB LDS -> 3 blocks/CU (12 waves/CU). agg compensates occupancy with
// x16-deep gather batches. Dynamic per-layer chunk counter (prefetched under
// the body) avoids static-split imbalance.
__global__ __launch_bounds__(256, 3) void layers_kernel(
    const unsigned short* __restrict__ x0bf,
    unsigned short* __restrict__ xA, unsigned short* __restrict__ xB,
    unsigned short* __restrict__ hpre,
    const int* __restrict__ rowptr, const int* __restrict__ rowend,
    const int* __restrict__ col,
    const unsigned short* __restrict__ W1T, const unsigned short* __restrict__ W2T,
    const float* __restrict__ bs1, const float* __restrict__ bs2,
    const int* __restrict__ batch, float* __restrict__ out,
    unsigned int* __restrict__ syncm) {
    __shared__ unsigned short Wl[128 * 128];  // 32 KB: W1 then W2
    __shared__ unsigned short Hl[64 * 128];   // 16 KB: hidden tile / agg scratch / pool red
    const int tid = threadIdx.x, bid = blockIdx.x;
    unsigned int tgt = 0;
    int* wctr = (int*)(syncm + 2);  // 4 per-layer work counters (memset'd per replay)
    const unsigned short* xin = x0bf;

    for (int l = 0; l < NL; l++) {
        // ---------------- agg phase: hpre = x + sum_neighbors(x) ----------------
        {
            int* s_next = (int*)Hl;  // Hl unused during agg
            int g = tid >> 4, lane = tid & 15;
            const uint4* base = (const uint4*)xin;
            if (tid == 0) *s_next = atomicAdd(&wctr[l], 1);
            __syncthreads();
            int gidx = *s_next;
            while (gidx < NCH) {
                __syncthreads();
                if (tid == 0) *s_next = atomicAdd(&wctr[l], 1);  // prefetch next chunk
                int node = gidx * 16 + g;
                float a[8];
#define ACC(V)                                                                          \
                a[0] += __uint_as_float(V.x << 16); a[1] += __uint_as_float(V.x & 0xFFFF0000u); \
                a[2] += __uint_as_float(V.y << 16); a[3] += __uint_as_float(V.y & 0xFFFF0000u); \
                a[4] += __uint_as_float(V.z << 16); a[5] += __uint_as_float(V.z & 0xFFFF0000u); \
                a[6] += __uint_as_float(V.w << 16); a[7] += __uint_as_float(V.w & 0xFFFF0000u)
                {
                    uint4 v = base[node * 16 + lane];
                    a[0] = __uint_as_float(v.x << 16); a[1] = __uint_as_float(v.x & 0xFFFF0000u);
                    a[2] = __uint_as_float(v.y << 16); a[3] = __uint_as_float(v.y & 0xFFFF0000u);
                    a[4] = __uint_as_float(v.z << 16); a[5] = __uint_as_float(v.z & 0xFFFF0000u);
                    a[6] = __uint_as_float(v.w << 16); a[7] = __uint_as_float(v.w & 0xFFFF0000u);
                }
                int s = rowptr[node], e = rowend[node];
                int i = s;
                for (; i + 16 <= e; i += 16) {
                    uint4 v[16];
#pragma unroll
                    for (int u = 0; u < 16; u++) v[u] = base[col[i + u] * 16 + lane];
#pragma unroll
                    for (int u = 0; u < 16; u++) { ACC(v[u]); }
                }
                for (; i + 8 <= e; i += 8) {
                    uint4 v[8];
#pragma unroll
                    for (int u = 0; u < 8; u++) v[u] = base[col[i + u] * 16 + lane];
#pragma unroll
                    for (int u = 0; u < 8; u++) { ACC(v[u]); }
                }
                for (; i < e; i++) {
                    uint4 v = base[col[i] * 16 + lane];
                    ACC(v);
                }
#undef ACC
                uint4 o;
                o.x = (unsigned int)f2bf(a[0]) | ((unsigned int)f2bf(a[1]) << 16);
                o.y = (unsigned int)f2bf(a[2]) | ((unsigned int)f2bf(a[3]) << 16);
                o.z = (unsigned int)f2bf(a[4]) | ((unsigned int)f2bf(a[5]) << 16);
                o.w = (unsigned int)f2bf(a[6]) | ((unsigned int)f2bf(a[7]) << 16);
                ((uint4*)hpre)[node * 16 + lane] = o;
                __syncthreads();
                gidx = *s_next;
            }
        }
        tgt += G2; grid_barrier(&syncm[1], tgt);

        // ---------------- mlp phase: xout = (relu(hpre@W1^T+b1))@W2^T + b2 ------
        unsigned short* xout = (l & 1) ? xB : xA;
        const unsigned short* W1 = W1T + (l << 14);
        const unsigned short* W2 = W2T + (l << 14);
        const float* b1 = bs1 + l * DD;
        const float* b2 = bs2 + l * DD;
        for (int t = bid; t < NT2; t += G2) {
            int wg = tid >> 6;
            int lane = tid & 63;
            int quad = lane >> 4;
            int li = lane & 15;
            int mg = wg >> 1, ng = wg & 1;  // wave = 32 rows x 64 cols
            int rowb = t * 64;

            {
                const uint4* wgl = (const uint4*)W1;
#pragma unroll
                for (int it = 0; it < 8; it++) {
                    int idx = it * 256 + tid;
                    int n = idx >> 4, kc = idx & 15;
                    *(uint4*)&Wl[n * 128 + ((kc * 8) ^ ((n & 7) << 3))] = wgl[idx];
                }
            }
            __syncthreads();

            floatx4 acc[4][2];
#pragma unroll
            for (int tn = 0; tn < 4; tn++)
#pragma unroll
                for (int mi = 0; mi < 2; mi++) acc[tn][mi] = (floatx4){0.f, 0.f, 0.f, 0.f};

#pragma unroll
            for (int kk = 0; kk < 4; kk++) {
                int kc = kk * 32 + quad * 8;
                short8 xf[2];
#pragma unroll
                for (int mi = 0; mi < 2; mi++) {
                    int ar = rowb + mg * 32 + mi * 16 + li;
                    xf[mi] = (ar < NN) ? *(const short8*)(hpre + (size_t)ar * DD + kc)
                                       : (short8){0, 0, 0, 0, 0, 0, 0, 0};
                }
#pragma unroll
                for (int tn = 0; tn < 4; tn++) {
                    int wr = ng * 64 + tn * 16 + li;
                    short8 wf = *(const short8*)&Wl[wr * 128 + (kc ^ ((wr & 7) << 3))];
#pragma unroll
                    for (int mi = 0; mi < 2; mi++)
                        acc[tn][mi] = __builtin_amdgcn_mfma_f32_16x16x32_bf16(wf, xf[mi], acc[tn][mi], 0, 0, 0);
                }
            }

#pragma unroll
            for (int tn = 0; tn < 4; tn++) {
                float4 bv = ((const float4*)b1)[ng * 16 + tn * 4 + quad];
#pragma unroll
                for (int mi = 0; mi < 2; mi++) {
                    int hr = mg * 32 + mi * 16 + li;
                    float v0 = fmaxf(acc[tn][mi][0] + bv.x, 0.f);
                    float v1 = fmaxf(acc[tn][mi][1] + bv.y, 0.f);
                    float v2 = fmaxf(acc[tn][mi][2] + bv.z, 0.f);
                    float v3 = fmaxf(acc[tn][mi][3] + bv.w, 0.f);
                    uint2 u;
                    u.x = (unsigned int)f2bf(v0) | ((unsigned int)f2bf(v1) << 16);
                    u.y = (unsigned int)f2bf(v2) | ((unsigned int)f2bf(v3) << 16);
                    int c = (ng * 64 + tn * 16 + quad * 4) ^ ((hr & 7) << 3);
                    *(uint2*)&Hl[hr * 128 + c] = u;
                }
            }
            __syncthreads();

            {
                const uint4* wgl = (const uint4*)W2;
#pragma unroll
                for (int it = 0; it < 8; it++) {
                    int idx = it * 256 + tid;
                    int n = idx >> 4, kc = idx & 15;
                    *(uint4*)&Wl[n * 128 + ((kc * 8) ^ ((n & 7) << 3))] = wgl[idx];
                }
            }
            __syncthreads();

#pragma unroll
            for (int tn = 0; tn < 4; tn++)
#pragma unroll
                for (int mi = 0; mi < 2; mi++) acc[tn][mi] = (floatx4){0.f, 0.f, 0.f, 0.f};

#pragma unroll
            for (int kk = 0; kk < 4; kk++) {
                int kc = kk * 32 + quad * 8;
                short8 hf[2];
#pragma unroll
                for (int mi = 0; mi < 2; mi++) {
                    int hr = mg * 32 + mi * 16 + li;
                    hf[mi] = *(const short8*)&Hl[hr * 128 + (kc ^ ((hr & 7) << 3))];
                }
#pragma unroll
                for (int tn = 0; tn < 4; tn++) {
                    int wr = ng * 64 + tn * 16 + li;
                    short8 wf = *(const short8*)&Wl[wr * 128 + (kc ^ ((wr & 7) << 3))];
#pragma unroll
                    for (int mi = 0; mi < 2; mi++)
                        acc[tn][mi] = __builtin_amdgcn_mfma_f32_16x16x32_bf16(wf, hf[mi], acc[tn][mi], 0, 0, 0);
                }
            }

#pragma unroll
            for (int tn = 0; tn < 4; tn++) {
                float4 bv = ((const float4*)b2)[ng * 16 + tn * 4 + quad];
#pragma unroll
                for (int mi = 0; mi < 2; mi++) {
                    int m = rowb + mg * 32 + mi * 16 + li;
                    if (m < NN) {
                        uint2 u;
                        u.x = (unsigned int)f2bf(acc[tn][mi][0] + bv.x) |
                              ((unsigned int)f2bf(acc[tn][mi][1] + bv.y) << 16);
                        u.y = (unsigned int)f2bf(acc[tn][mi][2] + bv.z) |
                              ((unsigned int)f2bf(acc[tn][mi][3] + bv.w) << 16);
                        *(uint2*)&xout[(size_t)m * DD + ng * 64 + tn * 16 + quad * 4] = u;
                    }
                }
            }
            __syncthreads();  // protect Wl/Hl reuse on 2nd tile iteration
        }
        tgt += G2; grid_barrier(&syncm[1], tgt);
        xin = xout;
    }

    // ---------------- pool: per-graph add over sorted batch ranges ----------
    if (bid < NG) {
        int gph = bid;
        int lo = 0, hi = NN;
        while (lo < hi) { int mid = (lo + hi) >> 1; if (batch[mid] < gph) lo = mid + 1; else hi = mid; }
        int s = lo;
        hi = NN;
        while (lo < hi) { int mid = (lo + hi) >> 1; if (batch[mid] < gph + 1) lo = mid + 1; else hi = mid; }
        int e = lo;
        int d = tid & 127, half = tid >> 7;
        float acc = 0.f;
        for (int i = s + half; i < e; i += 2) acc += bf2f(xin[(size_t)i * DD + d]);
        float* red = (float*)Hl;
        red[tid] = acc;
        __syncthreads();
        if (tid < 128) out[gph * DD + d] = red[d] + red[128 + d];
    }
}

extern "C" void kernel_launch(void* const* d_in, const int* in_sizes, int n_in,
                              void* d_out, int out_size, void* d_ws, size_t ws_size,
                              hipStream_t stream) {
    const float* x0 = (const float*)d_in[0];
    const int* edge = (const int*)d_in[1];
    const int* batch = (const int*)d_in[2];
    const float* Ws1 = (const float*)d_in[3];
    const float* bs1 = (const float*)d_in[4];
    const float* Ws2 = (const float*)d_in[5];
    const float* bs2 = (const float*)d_in[6];
    float* out = (float*)d_out;

    char* ws = (char*)d_ws;
    size_t off = 0;
    auto alloc = [&](size_t bytes) {
        void* p = ws + off;
        off += (bytes + 255) & ~(size_t)255;
        return p;
    };
    unsigned short* x0bf = (unsigned short*)alloc((size_t)NN * DD * 2);
    unsigned short* xA = (unsigned short*)alloc((size_t)NN * DD * 2);
    unsigned short* xB = (unsigned short*)alloc((size_t)NN * DD * 2);
    unsigned short* hpre = (unsigned short*)alloc((size_t)NN * DD * 2);
    int* col = (int*)alloc((size_t)NE * 4);
    int* ebuf = (int*)alloc((size_t)NE * 4);
    int* hist = (int*)alloc((size_t)HN * 4);
    int* bkoff = (int*)alloc((size_t)HN * 4);
    int* tsum = (int*)alloc((size_t)NBLK * 4);
    int* toff = (int*)alloc((size_t)NBLK * 4);
    int* rowptr = (int*)alloc((size_t)(NN + 1) * 4);
    int* rowend = (int*)alloc((size_t)NN * 4);
    unsigned short* W1T = (unsigned short*)alloc((size_t)NL * DD * DD * 2);
    unsigned short* W2T = (unsigned short*)alloc((size_t)NL * DD * DD * 2);
    unsigned int* syncm = (unsigned int*)alloc(256);

    (void)hipMemsetAsync(syncm, 0, 256, stream);
    build_kernel<<<G1, 256, 0, stream>>>(x0, edge, x0bf, Ws1, Ws2, W1T, W2T,
                                         hist, tsum, toff, bkoff, ebuf,
                                         rowptr, rowend, col, syncm);
    layers_kernel<<<G2, 256, 0, stream>>>(x0bf, xA, xB, hpre, rowptr, rowend, col,
                                          W1T, W2T, bs1, bs2, batch, out, syncm);
}

// Round 9
// 453.259 us; speedup vs baseline: 4.5298x; 3.1617x over previous
//
#include <hip/hip_runtime.h>

#define NN 50000
#define NE 1600000
#define DD 128
#define NL 4
#define NG 512
#define BSH 7       // bucket shift: 128 nodes (or srcs) per bucket/slice
#define BMSK 127
#define NBUK 391    // ceil(50000/128) — used for both dst buckets and src slices
#define NBLK 196    // edge blocks: ceil(NE/8192)
#define EPB 8192    // edges per block in bucket passes
#define HN (NBUK * NBLK)  // 76636
#define HT 150      // ceil(HN/512)
#define EPT 20      // bucket_csr: max edges per thread (seg mean 4096, max ~4350; cap 5120)

typedef __attribute__((ext_vector_type(8))) short short8;
typedef __attribute__((ext_vector_type(4))) float floatx4;

__device__ __forceinline__ unsigned short f2bf(float f) {
    unsigned int u = __float_as_uint(f);
    u += 0x7fffu + ((u >> 16) & 1u);
    return (unsigned short)(u >> 16);
}
__device__ __forceinline__ float bf2f(unsigned short u) {
    return __uint_as_float(((unsigned int)u) << 16);
}

// ---------- fp32 -> bf16 convert (layer-0 input) ----------
__global__ __launch_bounds__(256) void cvt_kernel(const float* __restrict__ x,
                                                  unsigned short* __restrict__ xbf) {
    int idx = blockIdx.x * 256 + threadIdx.x;  // one float4 per thread
    float4 f = ((const float4*)x)[idx];
    ushort4 o;
    o.x = f2bf(f.x); o.y = f2bf(f.y); o.z = f2bf(f.z); o.w = f2bf(f.w);
    ((ushort4*)xbf)[idx] = o;
}

// ---------- CSR build ----------
// R9(this session): R5-R8 proved persistent mega-fusion loses (barrier spin
// poisons the fabric; 33% occ). Back to R4 split dispatches + NEW: pre-sort
// edges by SRC (counting sort, packed (dst<<16)|src u32) so each row's
// neighbor list ends up src-ascending -> all agg blocks sweep x in lockstep
// -> live src window L2-fits -> FETCH toward the 102 MB compulsory floor
// (8 XCDs x 12.8 MB) instead of 154 MB.

// Pass A1: histogram by src slice (src>>7)
__global__ __launch_bounds__(512) void shist_kernel(const int* __restrict__ src,
                                                    int* __restrict__ hist) {
    __shared__ int h[NBUK];
    int tid = threadIdx.x;
    for (int i = tid; i < NBUK; i += 512) h[i] = 0;
    __syncthreads();
    int base = blockIdx.x * EPB;
#pragma unroll
    for (int it = 0; it < EPB / 512; it++) {
        int e = base + it * 512 + tid;
        if (e < NE) atomicAdd(&h[src[e] >> BSH], 1);
    }
    __syncthreads();
    for (int i = tid; i < NBUK; i += 512) hist[i * NBLK + blockIdx.x] = h[i];
}

// Scan chain (shared by pass A and pass B): exclusive scan of hist[HN]
__global__ __launch_bounds__(512) void sum_tiles_kernel(const int* __restrict__ in,
                                                        int* __restrict__ tsum, int n) {
    int i = blockIdx.x * 512 + threadIdx.x;
    __shared__ int s[512];
    s[threadIdx.x] = (i < n) ? in[i] : 0;
    __syncthreads();
    for (int off = 256; off > 0; off >>= 1) {
        if (threadIdx.x < off) s[threadIdx.x] += s[threadIdx.x + off];
        __syncthreads();
    }
    if (threadIdx.x == 0) tsum[blockIdx.x] = s[0];
}

__global__ __launch_bounds__(256) void scan_tiles_kernel(const int* __restrict__ tsum,
                                                         int* __restrict__ toff, int ntiles) {
    int t = threadIdx.x;
    __shared__ int s[256];
    int v = (t < ntiles) ? tsum[t] : 0;
    s[t] = v;
    __syncthreads();
    for (int off = 1; off < 256; off <<= 1) {
        int u = (t >= off) ? s[t - off] : 0;
        __syncthreads();
        s[t] += u;
        __syncthreads();
    }
    if (t < ntiles) toff[t] = s[t] - v;
}

__global__ __launch_bounds__(512) void scan_out_kernel(const int* __restrict__ in,
                                                       const int* __restrict__ toff,
                                                       int* __restrict__ out, int n) {
    int i = blockIdx.x * 512 + threadIdx.x;
    int t = threadIdx.x;
    int v = (i < n) ? in[i] : 0;
    __shared__ int s[512];
    s[t] = v;
    __syncthreads();
    for (int off = 1; off < 512; off <<= 1) {
        int u = (t >= off) ? s[t - off] : 0;
        __syncthreads();
        s[t] += u;
        __syncthreads();
    }
    if (i < n) out[i] = toff[blockIdx.x] + s[t] - v;
}

// Pass A2: scatter edges into src-sorted ebufA, packed (dst<<16)|src
__global__ __launch_bounds__(512) void sscatter_kernel(const int* __restrict__ src,
                                                       const int* __restrict__ dst,
                                                       const int* __restrict__ soff,
                                                       unsigned int* __restrict__ ebufA) {
    __shared__ int h[NBUK];
    int tid = threadIdx.x;
    for (int i = tid; i < NBUK; i += 512) h[i] = 0;
    __syncthreads();
    int base = blockIdx.x * EPB;
#pragma unroll
    for (int it = 0; it < EPB / 512; it++) {
        int e = base + it * 512 + tid;
        if (e < NE) {
            int s = src[e];
            int ss = s >> BSH;
            int p = atomicAdd(&h[ss], 1);
            ebufA[soff[ss * NBLK + blockIdx.x] + p] =
                ((unsigned int)dst[e] << 16) | (unsigned int)s;
        }
    }
}

// Pass B1: histogram by dst bucket, reading src-sorted packed edges
__global__ __launch_bounds__(512) void bhist_kernel(const unsigned int* __restrict__ ebufA,
                                                    int* __restrict__ hist) {
    __shared__ int h[NBUK];
    int tid = threadIdx.x;
    for (int i = tid; i < NBUK; i += 512) h[i] = 0;
    __syncthreads();
    int base = blockIdx.x * EPB;
#pragma unroll
    for (int it = 0; it < EPB / 512; it++) {
        int e = base + it * 512 + tid;
        if (e < NE) atomicAdd(&h[ebufA[e] >> (16 + BSH)], 1);
    }
    __syncthreads();
    for (int i = tid; i < NBUK; i += 512) hist[i * NBLK + blockIdx.x] = h[i];
}

// Pass B2: scatter into dst-bucketed ebuf, packed (src<<7)|(dst&127).
// Reading in ebufA (src-sorted) order makes each bucket segment src-ordered
// by construction (bid-major = src-slice-major).
__global__ __launch_bounds__(512) void bscatter_kernel(const unsigned int* __restrict__ ebufA,
                                                       const int* __restrict__ bkoff,
                                                       int* __restrict__ ebuf) {
    __shared__ int h[NBUK];
    int tid = threadIdx.x;
    for (int i = tid; i < NBUK; i += 512) h[i] = 0;
    __syncthreads();
    int base = blockIdx.x * EPB;
#pragma unroll
    for (int it = 0; it < EPB / 512; it++) {
        int e = base + it * 512 + tid;
        if (e < NE) {
            unsigned int pk = ebufA[e];
            int d = pk >> 16;
            int s = pk & 0xFFFF;
            int bu = d >> BSH;
            int p = atomicAdd(&h[bu], 1);
            ebuf[bkoff[bu * NBLK + blockIdx.x] + p] = (s << BSH) | (d & BMSK);
        }
    }
}

// Pass B3: one block per 128-node bucket. Single segment read into registers;
// pass-1 LDS atomic return IS the within-node rank (arrival order ~ src order,
// mixing window ~256 edges); scan cnt[128] -> rowptr/rowend; scatter from regs.
__global__ __launch_bounds__(256) void bucket_csr_kernel(const int* __restrict__ ebuf,
                                                         const int* __restrict__ bkoff,
                                                         int* __restrict__ rowptr,
                                                         int* __restrict__ rowend,
                                                         int* __restrict__ col) {
    __shared__ int cnt[128], exc[128], ebase[128];
    int b = blockIdx.x, tid = threadIdx.x;
    int segstart = bkoff[b * NBLK];
    int segend = (b < NBUK - 1) ? bkoff[(b + 1) * NBLK] : NE;
    if (tid < 128) cnt[tid] = 0;
    __syncthreads();
    int evr[EPT];
    int rnk[EPT];
#pragma unroll
    for (int j = 0; j < EPT; j++) {
        int i = segstart + tid + j * 256;
        if (i < segend) {
            int ev = ebuf[i];
            evr[j] = ev;
            rnk[j] = atomicAdd(&cnt[ev & BMSK], 1);
        } else {
            evr[j] = -1;
        }
    }
    __syncthreads();
    int v = (tid < 128) ? cnt[tid] : 0;
    if (tid < 128) exc[tid] = v;
    __syncthreads();
    for (int off = 1; off < 128; off <<= 1) {
        int u = (tid < 128 && tid >= off) ? exc[tid - off] : 0;
        __syncthreads();
        if (tid < 128) exc[tid] += u;
        __syncthreads();
    }
    if (tid < 128) {
        int excl = exc[tid] - v;  // exclusive prefix
        ebase[tid] = segstart + excl;
        int node = (b << BSH) + tid;
        if (node < NN) {
            rowptr[node] = segstart + excl;
            rowend[node] = segstart + excl + v;
        }
    }
    __syncthreads();
#pragma unroll
    for (int j = 0; j < EPT; j++) {
        if (evr[j] >= 0) {
            int low = evr[j] & BMSK;
            col[ebase[low] + rnk[j]] = ((unsigned)evr[j]) >> BSH;
        }
    }
}

// ---------- weight prep: fp32 [l][k][n] -> bf16 transposed [l][n][k] ----------
__global__ __launch_bounds__(256) void prep_kernel(const float* __restrict__ Ws1,
                                                   const float* __restrict__ Ws2,
                                                   unsigned short* __restrict__ W1T,
                                                   unsigned short* __restrict__ W2T) {
    int idx = blockIdx.x * 256 + threadIdx.x;  // [0, NL*DD*DD)
    int l = idx >> 14;
    int rem = idx & 16383;
    int k = rem >> 7;
    int n = rem & 127;
    int o = (l << 14) + (n << 7) + k;
    W1T[o] = f2bf(Ws1[idx]);
    W2T[o] = f2bf(Ws2[idx]);
}

// ---------- aggregation: hpre[i] = x[i] + sum_{j in N(i)} x[j], bf16 in/out ----------
// R4-exact body (best measured 53.0-53.8 us). Only the INPUT ordering changed:
// col lists are now src-ascending per row, so all blocks sweep x in lockstep.
__global__ __launch_bounds__(256) void agg_kernel(const unsigned short* __restrict__ xbf,
                                                  const int* __restrict__ rowptr,
                                                  const int* __restrict__ rowend,
                                                  const int* __restrict__ col,
                                                  unsigned short* __restrict__ hpre) {
    int g = threadIdx.x >> 4;   // 16 node-groups per block
    int lane = threadIdx.x & 15;
    int node = blockIdx.x * 16 + g;  // NN = 3125*16 exactly
    const uint4* base = (const uint4*)xbf;
    float a[8];
    {
        uint4 v = base[node * 16 + lane];
        a[0] = __uint_as_float(v.x << 16); a[1] = __uint_as_float(v.x & 0xFFFF0000u);
        a[2] = __uint_as_float(v.y << 16); a[3] = __uint_as_float(v.y & 0xFFFF0000u);
        a[4] = __uint_as_float(v.z << 16); a[5] = __uint_as_float(v.z & 0xFFFF0000u);
        a[6] = __uint_as_float(v.w << 16); a[7] = __uint_as_float(v.w & 0xFFFF0000u);
    }
    int s = rowptr[node], e = rowend[node];
    int i = s;
    for (; i + 8 <= e; i += 8) {
        uint4 v0 = base[col[i] * 16 + lane];
        uint4 v1 = base[col[i + 1] * 16 + lane];
        uint4 v2 = base[col[i + 2] * 16 + lane];
        uint4 v3 = base[col[i + 3] * 16 + lane];
        uint4 v4 = base[col[i + 4] * 16 + lane];
        uint4 v5 = base[col[i + 5] * 16 + lane];
        uint4 v6 = base[col[i + 6] * 16 + lane];
        uint4 v7 = base[col[i + 7] * 16 + lane];
#define ACC(V)                                                            \
        a[0] += __uint_as_float(V.x << 16); a[1] += __uint_as_float(V.x & 0xFFFF0000u); \
        a[2] += __uint_as_float(V.y << 16); a[3] += __uint_as_float(V.y & 0xFFFF0000u); \
        a[4] += __uint_as_float(V.z << 16); a[5] += __uint_as_float(V.z & 0xFFFF0000u); \
        a[6] += __uint_as_float(V.w << 16); a[7] += __uint_as_float(V.w & 0xFFFF0000u)
        ACC(v0); ACC(v1); ACC(v2); ACC(v3); ACC(v4); ACC(v5); ACC(v6); ACC(v7);
    }
    for (; i < e; i++) {
        uint4 v = base[col[i] * 16 + lane];
        ACC(v);
    }
#undef ACC
    uint4 o;
    o.x = (unsigned int)f2bf(a[0]) | ((unsigned int)f2bf(a[1]) << 16);
    o.y = (unsigned int)f2bf(a[2]) | ((unsigned int)f2bf(a[3]) << 16);
    o.z = (unsigned int)f2bf(a[4]) | ((unsigned int)f2bf(a[5]) << 16);
    o.w = (unsigned int)f2bf(a[6]) | ((unsigned int)f2bf(a[7]) << 16);
    ((uint4*)hpre)[node * 16 + lane] = o;
}

// ---------- fused MLP: O = (relu(A@W1^T+b1))@W2^T + b2, one block per 128 rows ----
// R4-exact (the 436 config). Swapped-operand MFMA: mfma(A=W_frag, B=x_frag)
// -> D[n][m], m = lane&15; lane holds 4 consecutive n -> packed 8B uint2
// stores. H never touches HBM. LDS XOR-swizzle in 16B units (G4/T2).
__global__ __launch_bounds__(256) void mlp_kernel(const unsigned short* __restrict__ A,
                                                  const unsigned short* __restrict__ W1,
                                                  const float* __restrict__ b1,
                                                  const unsigned short* __restrict__ W2,
                                                  const float* __restrict__ b2,
                                                  unsigned short* __restrict__ O) {
    __shared__ unsigned short Wl[128 * 128];  // 32 KB, holds W1 then W2
    __shared__ unsigned short Hl[128 * 128];  // 32 KB hidden tile
    int tid = threadIdx.x;
    int wg = tid >> 6;
    int lane = tid & 63;
    int quad = lane >> 4;
    int li = lane & 15;
    int mg = wg >> 1, ng = wg & 1;
    int rowb = blockIdx.x * 128;

    // ---- stage W1 ([n][k] bf16, swizzled) ----
    {
        const uint4* wgl = (const uint4*)W1;  // 2048 uint4
#pragma unroll
        for (int it = 0; it < 8; it++) {
            int idx = it * 256 + tid;
            int n = idx >> 4, kc = idx & 15;
            *(uint4*)&Wl[n * 128 + ((kc * 8) ^ ((n & 7) << 3))] = wgl[idx];
        }
    }
    __syncthreads();

    floatx4 acc[4][4];
#pragma unroll
    for (int tn = 0; tn < 4; tn++)
#pragma unroll
        for (int mi = 0; mi < 4; mi++) acc[tn][mi] = (floatx4){0.f, 0.f, 0.f, 0.f};

    // ---- GEMM1: D[n][m] = W1 . A^T ----
#pragma unroll
    for (int kk = 0; kk < 4; kk++) {
        int kc = kk * 32 + quad * 8;
        short8 xf[4];
#pragma unroll
        for (int mi = 0; mi < 4; mi++) {
            int ar = rowb + mg * 64 + mi * 16 + li;
            xf[mi] = (ar < NN) ? *(const short8*)(A + (size_t)ar * DD + kc)
                               : (short8){0, 0, 0, 0, 0, 0, 0, 0};
        }
#pragma unroll
        for (int tn = 0; tn < 4; tn++) {
            int wr = ng * 64 + tn * 16 + li;
            short8 wf = *(const short8*)&Wl[wr * 128 + (kc ^ ((wr & 7) << 3))];
#pragma unroll
            for (int mi = 0; mi < 4; mi++)
                acc[tn][mi] = __builtin_amdgcn_mfma_f32_16x16x32_bf16(wf, xf[mi], acc[tn][mi], 0, 0, 0);
        }
    }

    // ---- epilogue 1: +b1, relu, bf16 -> Hl ----
#pragma unroll
    for (int tn = 0; tn < 4; tn++) {
        float4 bv = ((const float4*)b1)[ng * 16 + tn * 4 + quad];
#pragma unroll
        for (int mi = 0; mi < 4; mi++) {
            int hr = mg * 64 + mi * 16 + li;
            float v0 = fmaxf(acc[tn][mi][0] + bv.x, 0.f);
            float v1 = fmaxf(acc[tn][mi][1] + bv.y, 0.f);
            float v2 = fmaxf(acc[tn][mi][2] + bv.z, 0.f);
            float v3 = fmaxf(acc[tn][mi][3] + bv.w, 0.f);
            uint2 u;
            u.x = (unsigned int)f2bf(v0) | ((unsigned int)f2bf(v1) << 16);
            u.y = (unsigned int)f2bf(v2) | ((unsigned int)f2bf(v3) << 16);
            int c = (ng * 64 + tn * 16 + quad * 4) ^ ((hr & 7) << 3);
            *(uint2*)&Hl[hr * 128 + c] = u;
        }
    }
    __syncthreads();  // Wl(W1) reads done + Hl fully written

    // ---- stage W2 over Wl ----
    {
        const uint4* wgl = (const uint4*)W2;
#pragma unroll
        for (int it = 0; it < 8; it++) {
            int idx = it * 256 + tid;
            int n = idx >> 4, kc = idx & 15;
            *(uint4*)&Wl[n * 128 + ((kc * 8) ^ ((n & 7) << 3))] = wgl[idx];
        }
    }
    __syncthreads();

    // ---- GEMM2: D[n2][m] = W2 . H^T ----
#pragma unroll
    for (int tn = 0; tn < 4; tn++)
#pragma unroll
        for (int mi = 0; mi < 4; mi++) acc[tn][mi] = (floatx4){0.f, 0.f, 0.f, 0.f};

#pragma unroll
    for (int kk = 0; kk < 4; kk++) {
        int kc = kk * 32 + quad * 8;
        short8 hf[4];
#pragma unroll
        for (int mi = 0; mi < 4; mi++) {
            int hr = mg * 64 + mi * 16 + li;
            hf[mi] = *(const short8*)&Hl[hr * 128 + (kc ^ ((hr & 7) << 3))];
        }
#pragma unroll
        for (int tn = 0; tn < 4; tn++) {
            int wr = ng * 64 + tn * 16 + li;
            short8 wf = *(const short8*)&Wl[wr * 128 + (kc ^ ((wr & 7) << 3))];
#pragma unroll
            for (int mi = 0; mi < 4; mi++)
                acc[tn][mi] = __builtin_amdgcn_mfma_f32_16x16x32_bf16(wf, hf[mi], acc[tn][mi], 0, 0, 0);
        }
    }

    // ---- epilogue 2: +b2, bf16 -> global O (8B packed stores) ----
#pragma unroll
    for (int tn = 0; tn < 4; tn++) {
        float4 bv = ((const float4*)b2)[ng * 16 + tn * 4 + quad];
#pragma unroll
        for (int mi = 0; mi < 4; mi++) {
            int m = rowb + mg * 64 + mi * 16 + li;
            if (m < NN) {
                uint2 u;
                u.x = (unsigned int)f2bf(acc[tn][mi][0] + bv.x) |
                      ((unsigned int)f2bf(acc[tn][mi][1] + bv.y) << 16);
                u.y = (unsigned int)f2bf(acc[tn][mi][2] + bv.z) |
                      ((unsigned int)f2bf(acc[tn][mi][3] + bv.w) << 16);
                *(uint2*)&O[(size_t)m * DD + ng * 64 + tn * 16 + quad * 4] = u;
            }
        }
    }
}

// ---------- global add pool: batch sorted -> per-graph contiguous range ----------
__global__ __launch_bounds__(128) void pool_kernel(const unsigned short* __restrict__ x,
                                                   const int* __restrict__ batch,
                                                   float* __restrict__ out) {
    int g = blockIdx.x;
    int lo = 0, hi = NN;
    while (lo < hi) { int mid = (lo + hi) >> 1; if (batch[mid] < g) lo = mid + 1; else hi = mid; }
    int s = lo;
    hi = NN;
    while (lo < hi) { int mid = (lo + hi) >> 1; if (batch[mid] < g + 1) lo = mid + 1; else hi = mid; }
    int e = lo;
    int d = threadIdx.x;
    float acc = 0.f;
    for (int i = s; i < e; i++) acc += bf2f(x[(size_t)i * DD + d]);
    out[g * DD + d] = acc;
}

extern "C" void kernel_launch(void* const* d_in, const int* in_sizes, int n_in,
                              void* d_out, int out_size, void* d_ws, size_t ws_size,
                              hipStream_t stream) {
    const float* x0 = (const float*)d_in[0];
    const int* edge = (const int*)d_in[1];
    const int* batch = (const int*)d_in[2];
    const float* Ws1 = (const float*)d_in[3];
    const float* bs1 = (const float*)d_in[4];
    const float* Ws2 = (const float*)d_in[5];
    const float* bs2 = (const float*)d_in[6];
    float* out = (float*)d_out;
    const int* src = edge;
    const int* dst = edge + NE;

    char* ws = (char*)d_ws;
    size_t off = 0;
    auto alloc = [&](size_t bytes) {
        void* p = ws + off;
        off += (bytes + 255) & ~(size_t)255;
        return p;
    };
    unsigned short* x0bf = (unsigned short*)alloc((size_t)NN * DD * 2);
    unsigned short* xA = (unsigned short*)alloc((size_t)NN * DD * 2);
    unsigned short* xB = (unsigned short*)alloc((size_t)NN * DD * 2);
    unsigned short* hpre = (unsigned short*)alloc((size_t)NN * DD * 2);
    int* col = (int*)alloc((size_t)NE * 4);
    int* ebuf = (int*)alloc((size_t)NE * 4);
    unsigned int* ebufA = (unsigned int*)alloc((size_t)NE * 4);
    int* hist = (int*)alloc((size_t)HN * 4);
    int* bkoff = (int*)alloc((size_t)HN * 4);
    int* soff = (int*)alloc((size_t)HN * 4);
    int* tsum = (int*)alloc((size_t)HT * 4);
    int* toff = (int*)alloc((size_t)HT * 4);
    int* rowptr = (int*)alloc((size_t)(NN + 1) * 4);
    int* rowend = (int*)alloc((size_t)NN * 4);
    unsigned short* W1T = (unsigned short*)alloc((size_t)NL * DD * DD * 2);
    unsigned short* W2T = (unsigned short*)alloc((size_t)NL * DD * DD * 2);

    cvt_kernel<<<(NN * DD / 4) / 256, 256, 0, stream>>>(x0, x0bf);
    // Pass A: sort edges by src into ebufA (packed (dst<<16)|src)
    shist_kernel<<<NBLK, 512, 0, stream>>>(src, hist);
    sum_tiles_kernel<<<HT, 512, 0, stream>>>(hist, tsum, HN);
    scan_tiles_kernel<<<1, 256, 0, stream>>>(tsum, toff, HT);
    scan_out_kernel<<<HT, 512, 0, stream>>>(hist, toff, soff, HN);
    sscatter_kernel<<<NBLK, 512, 0, stream>>>(src, dst, soff, ebufA);
    // Pass B: dst-bucket CSR build off the src-sorted edge stream
    bhist_kernel<<<NBLK, 512, 0, stream>>>(ebufA, hist);
    sum_tiles_kernel<<<HT, 512, 0, stream>>>(hist, tsum, HN);
    scan_tiles_kernel<<<1, 256, 0, stream>>>(tsum, toff, HT);
    scan_out_kernel<<<HT, 512, 0, stream>>>(hist, toff, bkoff, HN);
    bscatter_kernel<<<NBLK, 512, 0, stream>>>(ebufA, bkoff, ebuf);
    bucket_csr_kernel<<<NBUK, 256, 0, stream>>>(ebuf, bkoff, rowptr, rowend, col);
    prep_kernel<<<(NL * DD * DD) / 256, 256, 0, stream>>>(Ws1, Ws2, W1T, W2T);

    const unsigned short* xin = x0bf;
    unsigned short* bufs[2] = {xA, xB};
    const int mlp_grid = (NN + 127) / 128;  // 391
    for (int l = 0; l < NL; l++) {
        agg_kernel<<<NN / 16, 256, 0, stream>>>(xin, rowptr, rowend, col, hpre);
        unsigned short* xout = bufs[l & 1];
        mlp_kernel<<<mlp_grid, 256, 0, stream>>>(hpre, W1T + l * DD * DD, bs1 + l * DD,
                                                 W2T + l * DD * DD, bs2 + l * DD, xout);
        xin = xout;
    }
    pool_kernel<<<NG, 128, 0, stream>>>(xin, batch, out);
}

// Round 10
// 449.378 us; speedup vs baseline: 4.5689x; 1.0086x over previous
//
#include <hip/hip_runtime.h>

#define NN 50000
#define NE 1600000
#define DD 128
#define NL 4
#define NG 512
#define BSH 7       // bucket shift: 128 nodes (or srcs) per bucket/slice
#define BMSK 127
#define NBUK 391    // ceil(50000/128) — used for both dst buckets and src slices
#define NBLK 196    // edge blocks: ceil(NE/8192)
#define EPB 8192    // edges per block in bucket passes
#define HN (NBUK * NBLK)  // 76636
#define HT 150      // ceil(HN/512)
#define EPT 20      // bucket_csr: max edges per thread (seg mean 4096, max ~4350; cap 5120)
#define CVT_N (NN * DD / 4)    // 1600000 float4s
#define PREP_N (NL * DD * DD)  // 65536

typedef __attribute__((ext_vector_type(8))) short short8;
typedef __attribute__((ext_vector_type(4))) float floatx4;

__device__ __forceinline__ unsigned short f2bf(float f) {
    unsigned int u = __float_as_uint(f);
    u += 0x7fffu + ((u >> 16) & 1u);
    return (unsigned short)(u >> 16);
}
__device__ __forceinline__ float bf2f(unsigned short u) {
    return __uint_as_float(((unsigned int)u) << 16);
}

// ---------- prelude: fp32->bf16 cvt + weight transpose + src histogram ----------
// R10: three independent read-only-input phases fused into ONE dispatch
// (no ordering between them -> no barrier needed). Replaces 3 dispatches.
__global__ __launch_bounds__(512) void prelude_kernel(
    const float* __restrict__ x0, const float* __restrict__ Ws1,
    const float* __restrict__ Ws2, const int* __restrict__ src,
    unsigned short* __restrict__ xbf, unsigned short* __restrict__ W1T,
    unsigned short* __restrict__ W2T, int* __restrict__ hist) {
    __shared__ int h[NBUK];
    int tid = threadIdx.x, bid = blockIdx.x;
    int gid = bid * 512 + tid;
    // cvt: one float4 per thread per iteration
    for (int idx = gid; idx < CVT_N; idx += NBLK * 512) {
        float4 f = ((const float4*)x0)[idx];
        ushort4 o;
        o.x = f2bf(f.x); o.y = f2bf(f.y); o.z = f2bf(f.z); o.w = f2bf(f.w);
        ((ushort4*)xbf)[idx] = o;
    }
    // weight prep: fp32 [l][k][n] -> bf16 [l][n][k]
    for (int idx = gid; idx < PREP_N; idx += NBLK * 512) {
        int l = idx >> 14, rem = idx & 16383;
        int k = rem >> 7, n = rem & 127;
        int o = (l << 14) + (n << 7) + k;
        W1T[o] = f2bf(Ws1[idx]);
        W2T[o] = f2bf(Ws2[idx]);
    }
    // src-slice histogram (src>>7), per-(slice, block) counts
    for (int i = tid; i < NBUK; i += 512) h[i] = 0;
    __syncthreads();
    {
        int base = bid * EPB;
        int end = base + EPB; if (end > NE) end = NE;
        for (int e = base + tid; e < end; e += 512) atomicAdd(&h[src[e] >> BSH], 1);
    }
    __syncthreads();
    for (int i = tid; i < NBUK; i += 512) hist[i * NBLK + bid] = h[i];
}

// ---------- single-dispatch exclusive scan: decoupled aggregate lookback ------
// R10: replaces each 3-dispatch sum/scan/scan_out chain. 150 blocks (all
// co-resident on 256 CUs -> no progress hazard). Tile aggregate published as
// ONE atomic u32 with ready-bit packed in (flag+value same word -> no
// acquire/release needed — R6/R7 lesson: acquire spins poison the caches).
// Poll load is RELAXED; value rides in the same atomic word.
__global__ __launch_bounds__(512) void scan_lb_kernel(const int* __restrict__ in,
                                                      int* __restrict__ out,
                                                      unsigned int* __restrict__ tstat,
                                                      int n) {
    __shared__ int s[512];
    int b = blockIdx.x, tid = threadIdx.x;
    int i = b * 512 + tid;
    int v = (i < n) ? in[i] : 0;
    s[tid] = v;
    __syncthreads();
    for (int off = 1; off < 512; off <<= 1) {
        int u = (tid >= off) ? s[tid - off] : 0;
        __syncthreads();
        s[tid] += u;
        __syncthreads();
    }
    int incl = s[tid];
    int agg = s[511];
    if (tid == 0)
        __hip_atomic_store(&tstat[b], 0x80000000u | (unsigned int)agg,
                           __ATOMIC_RELAXED, __HIP_MEMORY_SCOPE_AGENT);
    // lookback: thread t (< b) polls predecessor t's aggregate
    unsigned int got = 0;
    if (tid < b) {
        unsigned int x = __hip_atomic_load(&tstat[tid], __ATOMIC_RELAXED,
                                           __HIP_MEMORY_SCOPE_AGENT);
        while (!(x & 0x80000000u)) {
            __builtin_amdgcn_s_sleep(1);
            x = __hip_atomic_load(&tstat[tid], __ATOMIC_RELAXED,
                                  __HIP_MEMORY_SCOPE_AGENT);
        }
        got = x & 0x7FFFFFFFu;
    }
    __syncthreads();  // everyone done reading s (incl/agg in regs)
    s[tid] = (int)got;
    __syncthreads();
    for (int off = 256; off > 0; off >>= 1) {
        if (tid < off) s[tid] += s[tid + off];
        __syncthreads();
    }
    int carry = s[0];
    if (i < n) out[i] = carry + incl - v;  // exclusive prefix
}

// ---------- CSR build (R9 structure, proven: agg FETCH 154->141.7 MB) ----------
// Edges pre-sorted by SRC (pass A) so each row's neighbor list is
// src-ascending -> agg blocks sweep x in lockstep -> L2-resident window.

// Pass A2: scatter edges into src-sorted ebufA, packed (dst<<16)|src
__global__ __launch_bounds__(512) void sscatter_kernel(const int* __restrict__ src,
                                                       const int* __restrict__ dst,
                                                       const int* __restrict__ soff,
                                                       unsigned int* __restrict__ ebufA) {
    __shared__ int h[NBUK];
    int tid = threadIdx.x;
    for (int i = tid; i < NBUK; i += 512) h[i] = 0;
    __syncthreads();
    int base = blockIdx.x * EPB;
#pragma unroll
    for (int it = 0; it < EPB / 512; it++) {
        int e = base + it * 512 + tid;
        if (e < NE) {
            int s = src[e];
            int ss = s >> BSH;
            int p = atomicAdd(&h[ss], 1);
            ebufA[soff[ss * NBLK + blockIdx.x] + p] =
                ((unsigned int)dst[e] << 16) | (unsigned int)s;
        }
    }
}

// Pass B1: histogram by dst bucket, reading src-sorted packed edges
__global__ __launch_bounds__(512) void bhist_kernel(const unsigned int* __restrict__ ebufA,
                                                    int* __restrict__ hist) {
    __shared__ int h[NBUK];
    int tid = threadIdx.x;
    for (int i = tid; i < NBUK; i += 512) h[i] = 0;
    __syncthreads();
    int base = blockIdx.x * EPB;
#pragma unroll
    for (int it = 0; it < EPB / 512; it++) {
        int e = base + it * 512 + tid;
        if (e < NE) atomicAdd(&h[ebufA[e] >> (16 + BSH)], 1);
    }
    __syncthreads();
    for (int i = tid; i < NBUK; i += 512) hist[i * NBLK + blockIdx.x] = h[i];
}

// Pass B2: scatter into dst-bucketed ebuf, packed (src<<7)|(dst&127).
// Reading in ebufA (src-sorted) order keeps each bucket segment src-ordered.
__global__ __launch_bounds__(512) void bscatter_kernel(const unsigned int* __restrict__ ebufA,
                                                       const int* __restrict__ bkoff,
                                                       int* __restrict__ ebuf) {
    __shared__ int h[NBUK];
    int tid = threadIdx.x;
    for (int i = tid; i < NBUK; i += 512) h[i] = 0;
    __syncthreads();
    int base = blockIdx.x * EPB;
#pragma unroll
    for (int it = 0; it < EPB / 512; it++) {
        int e = base + it * 512 + tid;
        if (e < NE) {
            unsigned int pk = ebufA[e];
            int d = pk >> 16;
            int s = pk & 0xFFFF;
            int bu = d >> BSH;
            int p = atomicAdd(&h[bu], 1);
            ebuf[bkoff[bu * NBLK + blockIdx.x] + p] = (s << BSH) | (d & BMSK);
        }
    }
}

// Pass B3: one block per 128-node bucket. Single segment read into registers;
// pass-1 LDS atomic return IS the within-node rank (arrival ~ src order);
// scan cnt[128] -> rowptr/rowend; scatter from regs.
__global__ __launch_bounds__(256) void bucket_csr_kernel(const int* __restrict__ ebuf,
                                                         const int* __restrict__ bkoff,
                                                         int* __restrict__ rowptr,
                                                         int* __restrict__ rowend,
                                                         int* __restrict__ col) {
    __shared__ int cnt[128], exc[128], ebase[128];
    int b = blockIdx.x, tid = threadIdx.x;
    int segstart = bkoff[b * NBLK];
    int segend = (b < NBUK - 1) ? bkoff[(b + 1) * NBLK] : NE;
    if (tid < 128) cnt[tid] = 0;
    __syncthreads();
    int evr[EPT];
    int rnk[EPT];
#pragma unroll
    for (int j = 0; j < EPT; j++) {
        int i = segstart + tid + j * 256;
        if (i < segend) {
            int ev = ebuf[i];
            evr[j] = ev;
            rnk[j] = atomicAdd(&cnt[ev & BMSK], 1);
        } else {
            evr[j] = -1;
        }
    }
    __syncthreads();
    int v = (tid < 128) ? cnt[tid] : 0;
    if (tid < 128) exc[tid] = v;
    __syncthreads();
    for (int off = 1; off < 128; off <<= 1) {
        int u = (tid < 128 && tid >= off) ? exc[tid - off] : 0;
        __syncthreads();
        if (tid < 128) exc[tid] += u;
        __syncthreads();
    }
    if (tid < 128) {
        int excl = exc[tid] - v;  // exclusive prefix
        ebase[tid] = segstart + excl;
        int node = (b << BSH) + tid;
        if (node < NN) {
            rowptr[node] = segstart + excl;
            rowend[node] = segstart + excl + v;
        }
    }
    __syncthreads();
#pragma unroll
    for (int j = 0; j < EPT; j++) {
        if (evr[j] >= 0) {
            int low = evr[j] & BMSK;
            col[ebase[low] + rnk[j]] = ((unsigned)evr[j]) >> BSH;
        }
    }
}

// ---------- aggregation: hpre[i] = x[i] + sum_{j in N(i)} x[j], bf16 in/out ----------
// R4-exact body; src-ascending col lists (R9) give lockstep x sweep.
__global__ __launch_bounds__(256) void agg_kernel(const unsigned short* __restrict__ xbf,
                                                  const int* __restrict__ rowptr,
                                                  const int* __restrict__ rowend,
                                                  const int* __restrict__ col,
                                                  unsigned short* __restrict__ hpre) {
    int g = threadIdx.x >> 4;   // 16 node-groups per block
    int lane = threadIdx.x & 15;
    int node = blockIdx.x * 16 + g;  // NN = 3125*16 exactly
    const uint4* base = (const uint4*)xbf;
    float a[8];
    {
        uint4 v = base[node * 16 + lane];
        a[0] = __uint_as_float(v.x << 16); a[1] = __uint_as_float(v.x & 0xFFFF0000u);
        a[2] = __uint_as_float(v.y << 16); a[3] = __uint_as_float(v.y & 0xFFFF0000u);
        a[4] = __uint_as_float(v.z << 16); a[5] = __uint_as_float(v.z & 0xFFFF0000u);
        a[6] = __uint_as_float(v.w << 16); a[7] = __uint_as_float(v.w & 0xFFFF0000u);
    }
    int s = rowptr[node], e = rowend[node];
    int i = s;
    for (; i + 8 <= e; i += 8) {
        uint4 v0 = base[col[i] * 16 + lane];
        uint4 v1 = base[col[i + 1] * 16 + lane];
        uint4 v2 = base[col[i + 2] * 16 + lane];
        uint4 v3 = base[col[i + 3] * 16 + lane];
        uint4 v4 = base[col[i + 4] * 16 + lane];
        uint4 v5 = base[col[i + 5] * 16 + lane];
        uint4 v6 = base[col[i + 6] * 16 + lane];
        uint4 v7 = base[col[i + 7] * 16 + lane];
#define ACC(V)                                                            \
        a[0] += __uint_as_float(V.x << 16); a[1] += __uint_as_float(V.x & 0xFFFF0000u); \
        a[2] += __uint_as_float(V.y << 16); a[3] += __uint_as_float(V.y & 0xFFFF0000u); \
        a[4] += __uint_as_float(V.z << 16); a[5] += __uint_as_float(V.z & 0xFFFF0000u); \
        a[6] += __uint_as_float(V.w << 16); a[7] += __uint_as_float(V.w & 0xFFFF0000u)
        ACC(v0); ACC(v1); ACC(v2); ACC(v3); ACC(v4); ACC(v5); ACC(v6); ACC(v7);
    }
    for (; i < e; i++) {
        uint4 v = base[col[i] * 16 + lane];
        ACC(v);
    }
#undef ACC
    uint4 o;
    o.x = (unsigned int)f2bf(a[0]) | ((unsigned int)f2bf(a[1]) << 16);
    o.y = (unsigned int)f2bf(a[2]) | ((unsigned int)f2bf(a[3]) << 16);
    o.z = (unsigned int)f2bf(a[4]) | ((unsigned int)f2bf(a[5]) << 16);
    o.w = (unsigned int)f2bf(a[6]) | ((unsigned int)f2bf(a[7]) << 16);
    ((uint4*)hpre)[node * 16 + lane] = o;
}

// ---------- fused MLP: O = (relu(A@W1^T+b1))@W2^T + b2, one block per 128 rows ----
// R4-exact. Swapped-operand MFMA: mfma(A=W_frag, B=x_frag) -> D[n][m],
// m = lane&15; lane holds 4 consecutive n -> packed 8B uint2 stores.
// H never touches HBM. LDS XOR-swizzle in 16B units (G4/T2).
__global__ __launch_bounds__(256) void mlp_kernel(const unsigned short* __restrict__ A,
                                                  const unsigned short* __restrict__ W1,
                                                  const float* __restrict__ b1,
                                                  const unsigned short* __restrict__ W2,
                                                  const float* __restrict__ b2,
                                                  unsigned short* __restrict__ O) {
    __shared__ unsigned short Wl[128 * 128];  // 32 KB, holds W1 then W2
    __shared__ unsigned short Hl[128 * 128];  // 32 KB hidden tile
    int tid = threadIdx.x;
    int wg = tid >> 6;
    int lane = tid & 63;
    int quad = lane >> 4;
    int li = lane & 15;
    int mg = wg >> 1, ng = wg & 1;
    int rowb = blockIdx.x * 128;

    // ---- stage W1 ([n][k] bf16, swizzled) ----
    {
        const uint4* wgl = (const uint4*)W1;  // 2048 uint4
#pragma unroll
        for (int it = 0; it < 8; it++) {
            int idx = it * 256 + tid;
            int n = idx >> 4, kc = idx & 15;
            *(uint4*)&Wl[n * 128 + ((kc * 8) ^ ((n & 7) << 3))] = wgl[idx];
        }
    }
    __syncthreads();

    floatx4 acc[4][4];
#pragma unroll
    for (int tn = 0; tn < 4; tn++)
#pragma unroll
        for (int mi = 0; mi < 4; mi++) acc[tn][mi] = (floatx4){0.f, 0.f, 0.f, 0.f};

    // ---- GEMM1: D[n][m] = W1 . A^T ----
#pragma unroll
    for (int kk = 0; kk < 4; kk++) {
        int kc = kk * 32 + quad * 8;
        short8 xf[4];
#pragma unroll
        for (int mi = 0; mi < 4; mi++) {
            int ar = rowb + mg * 64 + mi * 16 + li;
            xf[mi] = (ar < NN) ? *(const short8*)(A + (size_t)ar * DD + kc)
                               : (short8){0, 0, 0, 0, 0, 0, 0, 0};
        }
#pragma unroll
        for (int tn = 0; tn < 4; tn++) {
            int wr = ng * 64 + tn * 16 + li;
            short8 wf = *(const short8*)&Wl[wr * 128 + (kc ^ ((wr & 7) << 3))];
#pragma unroll
            for (int mi = 0; mi < 4; mi++)
                acc[tn][mi] = __builtin_amdgcn_mfma_f32_16x16x32_bf16(wf, xf[mi], acc[tn][mi], 0, 0, 0);
        }
    }

    // ---- epilogue 1: +b1, relu, bf16 -> Hl ----
#pragma unroll
    for (int tn = 0; tn < 4; tn++) {
        float4 bv = ((const float4*)b1)[ng * 16 + tn * 4 + quad];
#pragma unroll
        for (int mi = 0; mi < 4; mi++) {
            int hr = mg * 64 + mi * 16 + li;
            float v0 = fmaxf(acc[tn][mi][0] + bv.x, 0.f);
            float v1 = fmaxf(acc[tn][mi][1] + bv.y, 0.f);
            float v2 = fmaxf(acc[tn][mi][2] + bv.z, 0.f);
            float v3 = fmaxf(acc[tn][mi][3] + bv.w, 0.f);
            uint2 u;
            u.x = (unsigned int)f2bf(v0) | ((unsigned int)f2bf(v1) << 16);
            u.y = (unsigned int)f2bf(v2) | ((unsigned int)f2bf(v3) << 16);
            int c = (ng * 64 + tn * 16 + quad * 4) ^ ((hr & 7) << 3);
            *(uint2*)&Hl[hr * 128 + c] = u;
        }
    }
    __syncthreads();  // Wl(W1) reads done + Hl fully written

    // ---- stage W2 over Wl ----
    {
        const uint4* wgl = (const uint4*)W2;
#pragma unroll
        for (int it = 0; it < 8; it++) {
            int idx = it * 256 + tid;
            int n = idx >> 4, kc = idx & 15;
            *(uint4*)&Wl[n * 128 + ((kc * 8) ^ ((n & 7) << 3))] = wgl[idx];
        }
    }
    __syncthreads();

    // ---- GEMM2: D[n2][m] = W2 . H^T ----
#pragma unroll
    for (int tn = 0; tn < 4; tn++)
#pragma unroll
        for (int mi = 0; mi < 4; mi++) acc[tn][mi] = (floatx4){0.f, 0.f, 0.f, 0.f};

#pragma unroll
    for (int kk = 0; kk < 4; kk++) {
        int kc = kk * 32 + quad * 8;
        short8 hf[4];
#pragma unroll
        for (int mi = 0; mi < 4; mi++) {
            int hr = mg * 64 + mi * 16 + li;
            hf[mi] = *(const short8*)&Hl[hr * 128 + (kc ^ ((hr & 7) << 3))];
        }
#pragma unroll
        for (int tn = 0; tn < 4; tn++) {
            int wr = ng * 64 + tn * 16 + li;
            short8 wf = *(const short8*)&Wl[wr * 128 + (kc ^ ((wr & 7) << 3))];
#pragma unroll
            for (int mi = 0; mi < 4; mi++)
                acc[tn][mi] = __builtin_amdgcn_mfma_f32_16x16x32_bf16(wf, hf[mi], acc[tn][mi], 0, 0, 0);
        }
    }

    // ---- epilogue 2: +b2, bf16 -> global O (8B packed stores) ----
#pragma unroll
    for (int tn = 0; tn < 4; tn++) {
        float4 bv = ((const float4*)b2)[ng * 16 + tn * 4 + quad];
#pragma unroll
        for (int mi = 0; mi < 4; mi++) {
            int m = rowb + mg * 64 + mi * 16 + li;
            if (m < NN) {
                uint2 u;
                u.x = (unsigned int)f2bf(acc[tn][mi][0] + bv.x) |
                      ((unsigned int)f2bf(acc[tn][mi][1] + bv.y) << 16);
                u.y = (unsigned int)f2bf(acc[tn][mi][2] + bv.z) |
                      ((unsigned int)f2bf(acc[tn][mi][3] + bv.w) << 16);
                *(uint2*)&O[(size_t)m * DD + ng * 64 + tn * 16 + quad * 4] = u;
            }
        }
    }
}

// ---------- global add pool: batch sorted -> per-graph contiguous range ----------
__global__ __launch_bounds__(128) void pool_kernel(const unsigned short* __restrict__ x,
                                                   const int* __restrict__ batch,
                                                   float* __restrict__ out) {
    int g = blockIdx.x;
    int lo = 0, hi = NN;
    while (lo < hi) { int mid = (lo + hi) >> 1; if (batch[mid] < g) lo = mid + 1; else hi = mid; }
    int s = lo;
    hi = NN;
    while (lo < hi) { int mid = (lo + hi) >> 1; if (batch[mid] < g + 1) lo = mid + 1; else hi = mid; }
    int e = lo;
    int d = threadIdx.x;
    float acc = 0.f;
    for (int i = s; i < e; i++) acc += bf2f(x[(size_t)i * DD + d]);
    out[g * DD + d] = acc;
}

extern "C" void kernel_launch(void* const* d_in, const int* in_sizes, int n_in,
                              void* d_out, int out_size, void* d_ws, size_t ws_size,
                              hipStream_t stream) {
    const float* x0 = (const float*)d_in[0];
    const int* edge = (const int*)d_in[1];
    const int* batch = (const int*)d_in[2];
    const float* Ws1 = (const float*)d_in[3];
    const float* bs1 = (const float*)d_in[4];
    const float* Ws2 = (const float*)d_in[5];
    const float* bs2 = (const float*)d_in[6];
    float* out = (float*)d_out;
    const int* src = edge;
    const int* dst = edge + NE;

    char* ws = (char*)d_ws;
    size_t off = 0;
    auto alloc = [&](size_t bytes) {
        void* p = ws + off;
        off += (bytes + 255) & ~(size_t)255;
        return p;
    };
    unsigned short* x0bf = (unsigned short*)alloc((size_t)NN * DD * 2);
    unsigned short* xA = (unsigned short*)alloc((size_t)NN * DD * 2);
    unsigned short* xB = (unsigned short*)alloc((size_t)NN * DD * 2);
    unsigned short* hpre = (unsigned short*)alloc((size_t)NN * DD * 2);
    int* col = (int*)alloc((size_t)NE * 4);
    int* ebuf = (int*)alloc((size_t)NE * 4);
    unsigned int* ebufA = (unsigned int*)alloc((size_t)NE * 4);
    int* hist = (int*)alloc((size_t)HN * 4);
    int* bkoff = (int*)alloc((size_t)HN * 4);
    int* soff = (int*)alloc((size_t)HN * 4);
    int* rowptr = (int*)alloc((size_t)(NN + 1) * 4);
    int* rowend = (int*)alloc((size_t)NN * 4);
    unsigned short* W1T = (unsigned short*)alloc((size_t)NL * DD * DD * 2);
    unsigned short* W2T = (unsigned short*)alloc((size_t)NL * DD * DD * 2);
    unsigned int* tstat = (unsigned int*)alloc(4096);  // 2 x HT lookback slots
    unsigned int* tstatA = tstat;
    unsigned int* tstatB = tstat + 512;

    (void)hipMemsetAsync(tstat, 0, 4096, stream);
    prelude_kernel<<<NBLK, 512, 0, stream>>>(x0, Ws1, Ws2, src, x0bf, W1T, W2T, hist);
    scan_lb_kernel<<<HT, 512, 0, stream>>>(hist, soff, tstatA, HN);
    sscatter_kernel<<<NBLK, 512, 0, stream>>>(src, dst, soff, ebufA);
    bhist_kernel<<<NBLK, 512, 0, stream>>>(ebufA, hist);
    scan_lb_kernel<<<HT, 512, 0, stream>>>(hist, bkoff, tstatB, HN);
    bscatter_kernel<<<NBLK, 512, 0, stream>>>(ebufA, bkoff, ebuf);
    bucket_csr_kernel<<<NBUK, 256, 0, stream>>>(ebuf, bkoff, rowptr, rowend, col);

    const unsigned short* xin = x0bf;
    unsigned short* bufs[2] = {xA, xB};
    const int mlp_grid = (NN + 127) / 128;  // 391
    for (int l = 0; l < NL; l++) {
        agg_kernel<<<NN / 16, 256, 0, stream>>>(xin, rowptr, rowend, col, hpre);
        unsigned short* xout = bufs[l & 1];
        mlp_kernel<<<mlp_grid, 256, 0, stream>>>(hpre, W1T + l * DD * DD, bs1 + l * DD,
                                                 W2T + l * DD * DD, bs2 + l * DD, xout);
        xin = xout;
    }
    pool_kernel<<<NG, 128, 0, stream>>>(xin, batch, out);
}

// Round 11
// 434.826 us; speedup vs baseline: 4.7218x; 1.0335x over previous
//
#include <hip/hip_runtime.h>

#define NN 50000
#define NE 1600000
#define DD 128
#define NL 4
#define NG 512
#define BSH 7       // bucket shift: 128 nodes per bucket
#define BMSK 127
#define NBUK 391    // ceil(50000/128)
#define NBLK 196    // edge blocks: ceil(NE/8192)
#define EPB 8192    // edges per block in bucket passes
#define HN (NBUK * NBLK)  // 76636
#define HT 150      // ceil(HN/512)
#define EPT 20      // bucket_csr: max edges per thread (seg mean 4096, max ~4350; cap 5120)
#define CVT_N (NN * DD / 4)    // 1600000 float4s
#define PREP_N (NL * DD * DD)  // 65536

typedef __attribute__((ext_vector_type(8))) short short8;
typedef __attribute__((ext_vector_type(4))) float floatx4;

__device__ __forceinline__ unsigned short f2bf(float f) {
    unsigned int u = __float_as_uint(f);
    u += 0x7fffu + ((u >> 16) & 1u);
    return (unsigned short)(u >> 16);
}
__device__ __forceinline__ float bf2f(unsigned short u) {
    return __uint_as_float(((unsigned int)u) << 16);
}

// ---------- prelude: fp32->bf16 cvt + weight transpose + dst histogram ----------
// R11: R9/R10 proved the src-sort is net-negative (buys agg 12 us, costs ~25)
// and marginal dispatch cost is ~1 us. Keep only the verified-positive fusion:
// three independent read-only-input phases in ONE dispatch.
__global__ __launch_bounds__(512) void prelude_kernel(
    const float* __restrict__ x0, const float* __restrict__ Ws1,
    const float* __restrict__ Ws2, const int* __restrict__ dst,
    unsigned short* __restrict__ xbf, unsigned short* __restrict__ W1T,
    unsigned short* __restrict__ W2T, int* __restrict__ hist) {
    __shared__ int h[NBUK];
    int tid = threadIdx.x, bid = blockIdx.x;
    int gid = bid * 512 + tid;
    // cvt: one float4 per thread per iteration
    for (int idx = gid; idx < CVT_N; idx += NBLK * 512) {
        float4 f = ((const float4*)x0)[idx];
        ushort4 o;
        o.x = f2bf(f.x); o.y = f2bf(f.y); o.z = f2bf(f.z); o.w = f2bf(f.w);
        ((ushort4*)xbf)[idx] = o;
    }
    // weight prep: fp32 [l][k][n] -> bf16 [l][n][k]
    for (int idx = gid; idx < PREP_N; idx += NBLK * 512) {
        int l = idx >> 14, rem = idx & 16383;
        int k = rem >> 7, n = rem & 127;
        int o = (l << 14) + (n << 7) + k;
        W1T[o] = f2bf(Ws1[idx]);
        W2T[o] = f2bf(Ws2[idx]);
    }
    // dst-bucket histogram (dst>>7), per-(bucket, block) counts
    for (int i = tid; i < NBUK; i += 512) h[i] = 0;
    __syncthreads();
    {
        int base = bid * EPB;
        int end = base + EPB; if (end > NE) end = NE;
        for (int e = base + tid; e < end; e += 512) atomicAdd(&h[dst[e] >> BSH], 1);
    }
    __syncthreads();
    for (int i = tid; i < NBUK; i += 512) hist[i * NBLK + bid] = h[i];
}

// ---------- single-dispatch exclusive scan: decoupled aggregate lookback ------
// Replaces the 3-dispatch sum/scan/scan_out chain (correct in R10 x2).
// 150 blocks all co-resident -> no progress hazard. Tile aggregate published
// as ONE atomic u32 with ready-bit packed in (flag+value same word -> no
// acquire/release needed; RELAXED poll — R6/R7 lesson: acquire spins poison
// the caches).
__global__ __launch_bounds__(512) void scan_lb_kernel(const int* __restrict__ in,
                                                      int* __restrict__ out,
                                                      unsigned int* __restrict__ tstat,
                                                      int n) {
    __shared__ int s[512];
    int b = blockIdx.x, tid = threadIdx.x;
    int i = b * 512 + tid;
    int v = (i < n) ? in[i] : 0;
    s[tid] = v;
    __syncthreads();
    for (int off = 1; off < 512; off <<= 1) {
        int u = (tid >= off) ? s[tid - off] : 0;
        __syncthreads();
        s[tid] += u;
        __syncthreads();
    }
    int incl = s[tid];
    int agg = s[511];
    if (tid == 0)
        __hip_atomic_store(&tstat[b], 0x80000000u | (unsigned int)agg,
                           __ATOMIC_RELAXED, __HIP_MEMORY_SCOPE_AGENT);
    // lookback: thread t (< b) polls predecessor t's aggregate
    unsigned int got = 0;
    if (tid < b) {
        unsigned int x = __hip_atomic_load(&tstat[tid], __ATOMIC_RELAXED,
                                           __HIP_MEMORY_SCOPE_AGENT);
        while (!(x & 0x80000000u)) {
            __builtin_amdgcn_s_sleep(1);
            x = __hip_atomic_load(&tstat[tid], __ATOMIC_RELAXED,
                                  __HIP_MEMORY_SCOPE_AGENT);
        }
        got = x & 0x7FFFFFFFu;
    }
    __syncthreads();  // everyone done reading s (incl/agg in regs)
    s[tid] = (int)got;
    __syncthreads();
    for (int off = 256; off > 0; off >>= 1) {
        if (tid < off) s[tid] += s[tid + off];
        __syncthreads();
    }
    int carry = s[0];
    if (i < n) out[i] = carry + incl - v;  // exclusive prefix
}

// ---------- Pass 3: scatter edges into dst-bucketed ebuf, packed (src<<7)|(dst&127) ----
__global__ __launch_bounds__(512) void bscatter_kernel(const int* __restrict__ src,
                                                       const int* __restrict__ dst,
                                                       const int* __restrict__ bkoff,
                                                       int* __restrict__ ebuf) {
    __shared__ int h[NBUK];
    int tid = threadIdx.x;
    for (int i = tid; i < NBUK; i += 512) h[i] = 0;
    __syncthreads();
    int base = blockIdx.x * EPB;
#pragma unroll
    for (int it = 0; it < EPB / 512; it++) {
        int e = base + it * 512 + tid;
        if (e < NE) {
            int d = dst[e];
            int bu = d >> BSH;
            int p = atomicAdd(&h[bu], 1);
            ebuf[bkoff[bu * NBLK + blockIdx.x] + p] = (src[e] << BSH) | (d & BMSK);
        }
    }
}

// ---------- Pass 4: one block per 128-node bucket (R4-exact) ----------
// Single segment read into registers; pass-1 LDS atomic return IS the
// within-node rank; scan cnt[128] -> rowptr/rowend; scatter from regs.
__global__ __launch_bounds__(256) void bucket_csr_kernel(const int* __restrict__ ebuf,
                                                         const int* __restrict__ bkoff,
                                                         int* __restrict__ rowptr,
                                                         int* __restrict__ rowend,
                                                         int* __restrict__ col) {
    __shared__ int cnt[128], exc[128], ebase[128];
    int b = blockIdx.x, tid = threadIdx.x;
    int segstart = bkoff[b * NBLK];
    int segend = (b < NBUK - 1) ? bkoff[(b + 1) * NBLK] : NE;
    if (tid < 128) cnt[tid] = 0;
    __syncthreads();
    int evr[EPT];
    int rnk[EPT];
#pragma unroll
    for (int j = 0; j < EPT; j++) {
        int i = segstart + tid + j * 256;
        if (i < segend) {
            int ev = ebuf[i];
            evr[j] = ev;
            rnk[j] = atomicAdd(&cnt[ev & BMSK], 1);
        } else {
            evr[j] = -1;
        }
    }
    __syncthreads();
    int v = (tid < 128) ? cnt[tid] : 0;
    if (tid < 128) exc[tid] = v;
    __syncthreads();
    for (int off = 1; off < 128; off <<= 1) {
        int u = (tid < 128 && tid >= off) ? exc[tid - off] : 0;
        __syncthreads();
        if (tid < 128) exc[tid] += u;
        __syncthreads();
    }
    if (tid < 128) {
        int excl = exc[tid] - v;  // exclusive prefix
        ebase[tid] = segstart + excl;
        int node = (b << BSH) + tid;
        if (node < NN) {
            rowptr[node] = segstart + excl;
            rowend[node] = segstart + excl + v;
        }
    }
    __syncthreads();
#pragma unroll
    for (int j = 0; j < EPT; j++) {
        if (evr[j] >= 0) {
            int low = evr[j] & BMSK;
            col[ebase[low] + rnk[j]] = ((unsigned)evr[j]) >> BSH;
        }
    }
}

// ---------- aggregation: hpre[i] = x[i] + sum_{j in N(i)} x[j], bf16 in/out ----------
// R4-exact (best total: 436.3). Fabric-gather-bound at ~3.1 TB/s / ~154 MB:
// established floor across 5 structural variants (R1/R2/R3/R9/R10).
__global__ __launch_bounds__(256) void agg_kernel(const unsigned short* __restrict__ xbf,
                                                  const int* __restrict__ rowptr,
                                                  const int* __restrict__ rowend,
                                                  const int* __restrict__ col,
                                                  unsigned short* __restrict__ hpre) {
    int g = threadIdx.x >> 4;   // 16 node-groups per block
    int lane = threadIdx.x & 15;
    int node = blockIdx.x * 16 + g;  // NN = 3125*16 exactly
    const uint4* base = (const uint4*)xbf;
    float a[8];
    {
        uint4 v = base[node * 16 + lane];
        a[0] = __uint_as_float(v.x << 16); a[1] = __uint_as_float(v.x & 0xFFFF0000u);
        a[2] = __uint_as_float(v.y << 16); a[3] = __uint_as_float(v.y & 0xFFFF0000u);
        a[4] = __uint_as_float(v.z << 16); a[5] = __uint_as_float(v.z & 0xFFFF0000u);
        a[6] = __uint_as_float(v.w << 16); a[7] = __uint_as_float(v.w & 0xFFFF0000u);
    }
    int s = rowptr[node], e = rowend[node];
    int i = s;
    for (; i + 8 <= e; i += 8) {
        uint4 v0 = base[col[i] * 16 + lane];
        uint4 v1 = base[col[i + 1] * 16 + lane];
        uint4 v2 = base[col[i + 2] * 16 + lane];
        uint4 v3 = base[col[i + 3] * 16 + lane];
        uint4 v4 = base[col[i + 4] * 16 + lane];
        uint4 v5 = base[col[i + 5] * 16 + lane];
        uint4 v6 = base[col[i + 6] * 16 + lane];
        uint4 v7 = base[col[i + 7] * 16 + lane];
#define ACC(V)                                                            \
        a[0] += __uint_as_float(V.x << 16); a[1] += __uint_as_float(V.x & 0xFFFF0000u); \
        a[2] += __uint_as_float(V.y << 16); a[3] += __uint_as_float(V.y & 0xFFFF0000u); \
        a[4] += __uint_as_float(V.z << 16); a[5] += __uint_as_float(V.z & 0xFFFF0000u); \
        a[6] += __uint_as_float(V.w << 16); a[7] += __uint_as_float(V.w & 0xFFFF0000u)
        ACC(v0); ACC(v1); ACC(v2); ACC(v3); ACC(v4); ACC(v5); ACC(v6); ACC(v7);
    }
    for (; i < e; i++) {
        uint4 v = base[col[i] * 16 + lane];
        ACC(v);
    }
#undef ACC
    uint4 o;
    o.x = (unsigned int)f2bf(a[0]) | ((unsigned int)f2bf(a[1]) << 16);
    o.y = (unsigned int)f2bf(a[2]) | ((unsigned int)f2bf(a[3]) << 16);
    o.z = (unsigned int)f2bf(a[4]) | ((unsigned int)f2bf(a[5]) << 16);
    o.w = (unsigned int)f2bf(a[6]) | ((unsigned int)f2bf(a[7]) << 16);
    ((uint4*)hpre)[node * 16 + lane] = o;
}

// ---------- fused MLP: O = (relu(A@W1^T+b1))@W2^T + b2, one block per 128 rows ----
// R4-exact. Swapped-operand MFMA: mfma(A=W_frag, B=x_frag) -> D[n][m],
// m = lane&15; lane holds 4 consecutive n -> packed 8B uint2 stores.
// H never touches HBM. LDS XOR-swizzle in 16B units (G4/T2).
__global__ __launch_bounds__(256) void mlp_kernel(const unsigned short* __restrict__ A,
                                                  const unsigned short* __restrict__ W1,
                                                  const float* __restrict__ b1,
                                                  const unsigned short* __restrict__ W2,
                                                  const float* __restrict__ b2,
                                                  unsigned short* __restrict__ O) {
    __shared__ unsigned short Wl[128 * 128];  // 32 KB, holds W1 then W2
    __shared__ unsigned short Hl[128 * 128];  // 32 KB hidden tile
    int tid = threadIdx.x;
    int wg = tid >> 6;
    int lane = tid & 63;
    int quad = lane >> 4;
    int li = lane & 15;
    int mg = wg >> 1, ng = wg & 1;
    int rowb = blockIdx.x * 128;

    // ---- stage W1 ([n][k] bf16, swizzled) ----
    {
        const uint4* wgl = (const uint4*)W1;  // 2048 uint4
#pragma unroll
        for (int it = 0; it < 8; it++) {
            int idx = it * 256 + tid;
            int n = idx >> 4, kc = idx & 15;
            *(uint4*)&Wl[n * 128 + ((kc * 8) ^ ((n & 7) << 3))] = wgl[idx];
        }
    }
    __syncthreads();

    floatx4 acc[4][4];
#pragma unroll
    for (int tn = 0; tn < 4; tn++)
#pragma unroll
        for (int mi = 0; mi < 4; mi++) acc[tn][mi] = (floatx4){0.f, 0.f, 0.f, 0.f};

    // ---- GEMM1: D[n][m] = W1 . A^T ----
#pragma unroll
    for (int kk = 0; kk < 4; kk++) {
        int kc = kk * 32 + quad * 8;
        short8 xf[4];
#pragma unroll
        for (int mi = 0; mi < 4; mi++) {
            int ar = rowb + mg * 64 + mi * 16 + li;
            xf[mi] = (ar < NN) ? *(const short8*)(A + (size_t)ar * DD + kc)
                               : (short8){0, 0, 0, 0, 0, 0, 0, 0};
        }
#pragma unroll
        for (int tn = 0; tn < 4; tn++) {
            int wr = ng * 64 + tn * 16 + li;
            short8 wf = *(const short8*)&Wl[wr * 128 + (kc ^ ((wr & 7) << 3))];
#pragma unroll
            for (int mi = 0; mi < 4; mi++)
                acc[tn][mi] = __builtin_amdgcn_mfma_f32_16x16x32_bf16(wf, xf[mi], acc[tn][mi], 0, 0, 0);
        }
    }

    // ---- epilogue 1: +b1, relu, bf16 -> Hl ----
#pragma unroll
    for (int tn = 0; tn < 4; tn++) {
        float4 bv = ((const float4*)b1)[ng * 16 + tn * 4 + quad];
#pragma unroll
        for (int mi = 0; mi < 4; mi++) {
            int hr = mg * 64 + mi * 16 + li;
            float v0 = fmaxf(acc[tn][mi][0] + bv.x, 0.f);
            float v1 = fmaxf(acc[tn][mi][1] + bv.y, 0.f);
            float v2 = fmaxf(acc[tn][mi][2] + bv.z, 0.f);
            float v3 = fmaxf(acc[tn][mi][3] + bv.w, 0.f);
            uint2 u;
            u.x = (unsigned int)f2bf(v0) | ((unsigned int)f2bf(v1) << 16);
            u.y = (unsigned int)f2bf(v2) | ((unsigned int)f2bf(v3) << 16);
            int c = (ng * 64 + tn * 16 + quad * 4) ^ ((hr & 7) << 3);
            *(uint2*)&Hl[hr * 128 + c] = u;
        }
    }
    __syncthreads();  // Wl(W1) reads done + Hl fully written

    // ---- stage W2 over Wl ----
    {
        const uint4* wgl = (const uint4*)W2;
#pragma unroll
        for (int it = 0; it < 8; it++) {
            int idx = it * 256 + tid;
            int n = idx >> 4, kc = idx & 15;
            *(uint4*)&Wl[n * 128 + ((kc * 8) ^ ((n & 7) << 3))] = wgl[idx];
        }
    }
    __syncthreads();

    // ---- GEMM2: D[n2][m] = W2 . H^T ----
#pragma unroll
    for (int tn = 0; tn < 4; tn++)
#pragma unroll
        for (int mi = 0; mi < 4; mi++) acc[tn][mi] = (floatx4){0.f, 0.f, 0.f, 0.f};

#pragma unroll
    for (int kk = 0; kk < 4; kk++) {
        int kc = kk * 32 + quad * 8;
        short8 hf[4];
#pragma unroll
        for (int mi = 0; mi < 4; mi++) {
            int hr = mg * 64 + mi * 16 + li;
            hf[mi] = *(const short8*)&Hl[hr * 128 + (kc ^ ((hr & 7) << 3))];
        }
#pragma unroll
        for (int tn = 0; tn < 4; tn++) {
            int wr = ng * 64 + tn * 16 + li;
            short8 wf = *(const short8*)&Wl[wr * 128 + (kc ^ ((wr & 7) << 3))];
#pragma unroll
            for (int mi = 0; mi < 4; mi++)
                acc[tn][mi] = __builtin_amdgcn_mfma_f32_16x16x32_bf16(wf, hf[mi], acc[tn][mi], 0, 0, 0);
        }
    }

    // ---- epilogue 2: +b2, bf16 -> global O (8B packed stores) ----
#pragma unroll
    for (int tn = 0; tn < 4; tn++) {
        float4 bv = ((const float4*)b2)[ng * 16 + tn * 4 + quad];
#pragma unroll
        for (int mi = 0; mi < 4; mi++) {
            int m = rowb + mg * 64 + mi * 16 + li;
            if (m < NN) {
                uint2 u;
                u.x = (unsigned int)f2bf(acc[tn][mi][0] + bv.x) |
                      ((unsigned int)f2bf(acc[tn][mi][1] + bv.y) << 16);
                u.y = (unsigned int)f2bf(acc[tn][mi][2] + bv.z) |
                      ((unsigned int)f2bf(acc[tn][mi][3] + bv.w) << 16);
                *(uint2*)&O[(size_t)m * DD + ng * 64 + tn * 16 + quad * 4] = u;
            }
        }
    }
}

// ---------- global add pool: batch sorted -> per-graph contiguous range ----------
__global__ __launch_bounds__(128) void pool_kernel(const unsigned short* __restrict__ x,
                                                   const int* __restrict__ batch,
                                                   float* __restrict__ out) {
    int g = blockIdx.x;
    int lo = 0, hi = NN;
    while (lo < hi) { int mid = (lo + hi) >> 1; if (batch[mid] < g) lo = mid + 1; else hi = mid; }
    int s = lo;
    hi = NN;
    while (lo < hi) { int mid = (lo + hi) >> 1; if (batch[mid] < g + 1) lo = mid + 1; else hi = mid; }
    int e = lo;
    int d = threadIdx.x;
    float acc = 0.f;
    for (int i = s; i < e; i++) acc += bf2f(x[(size_t)i * DD + d]);
    out[g * DD + d] = acc;
}

extern "C" void kernel_launch(void* const* d_in, const int* in_sizes, int n_in,
                              void* d_out, int out_size, void* d_ws, size_t ws_size,
                              hipStream_t stream) {
    const float* x0 = (const float*)d_in[0];
    const int* edge = (const int*)d_in[1];
    const int* batch = (const int*)d_in[2];
    const float* Ws1 = (const float*)d_in[3];
    const float* bs1 = (const float*)d_in[4];
    const float* Ws2 = (const float*)d_in[5];
    const float* bs2 = (const float*)d_in[6];
    float* out = (float*)d_out;
    const int* src = edge;
    const int* dst = edge + NE;

    char* ws = (char*)d_ws;
    size_t off = 0;
    auto alloc = [&](size_t bytes) {
        void* p = ws + off;
        off += (bytes + 255) & ~(size_t)255;
        return p;
    };
    unsigned short* x0bf = (unsigned short*)alloc((size_t)NN * DD * 2);
    unsigned short* xA = (unsigned short*)alloc((size_t)NN * DD * 2);
    unsigned short* xB = (unsigned short*)alloc((size_t)NN * DD * 2);
    unsigned short* hpre = (unsigned short*)alloc((size_t)NN * DD * 2);
    int* col = (int*)alloc((size_t)NE * 4);
    int* ebuf = (int*)alloc((size_t)NE * 4);
    int* hist = (int*)alloc((size_t)HN * 4);
    int* bkoff = (int*)alloc((size_t)HN * 4);
    int* rowptr = (int*)alloc((size_t)(NN + 1) * 4);
    int* rowend = (int*)alloc((size_t)NN * 4);
    unsigned short* W1T = (unsigned short*)alloc((size_t)NL * DD * DD * 2);
    unsigned short* W2T = (unsigned short*)alloc((size_t)NL * DD * DD * 2);
    unsigned int* tstat = (unsigned int*)alloc(2048);  // HT lookback slots

    (void)hipMemsetAsync(tstat, 0, 2048, stream);
    prelude_kernel<<<NBLK, 512, 0, stream>>>(x0, Ws1, Ws2, dst, x0bf, W1T, W2T, hist);
    scan_lb_kernel<<<HT, 512, 0, stream>>>(hist, bkoff, tstat, HN);
    bscatter_kernel<<<NBLK, 512, 0, stream>>>(src, dst, bkoff, ebuf);
    bucket_csr_kernel<<<NBUK, 256, 0, stream>>>(ebuf, bkoff, rowptr, rowend, col);

    const unsigned short* xin = x0bf;
    unsigned short* bufs[2] = {xA, xB};
    const int mlp_grid = (NN + 127) / 128;  // 391
    for (int l = 0; l < NL; l++) {
        agg_kernel<<<NN / 16, 256, 0, stream>>>(xin, rowptr, rowend, col, hpre);
        unsigned short* xout = bufs[l & 1];
        mlp_kernel<<<mlp_grid, 256, 0, stream>>>(hpre, W1T + l * DD * DD, bs1 + l * DD,
                                                 W2T + l * DD * DD, bs2 + l * DD, xout);
        xin = xout;
    }
    pool_kernel<<<NG, 128, 0, stream>>>(xin, batch, out);
}

// Round 12
// 410.982 us; speedup vs baseline: 4.9957x; 1.0580x over previous
//
#include <hip/hip_runtime.h>

#define NN 50000
#define NE 1600000
#define DD 128
#define NL 4
#define NG 512
#define BSH 7       // bucket shift: 128 nodes per bucket
#define BMSK 127
#define NBUK 391    // ceil(50000/128)
#define NBLK 196    // edge blocks: ceil(NE/8192)
#define EPB 8192    // edges per block in bucket passes
#define HN (NBUK * NBLK)  // 76636
#define HT 150      // ceil(HN/512)
#define EPT 20      // bucket_csr: max edges per thread (seg mean 4096, max ~4350; cap 5120)
#define CVT_N (NN * DD / 4)    // 1600000 float4s
#define PREP_N (NL * DD * DD)  // 65536

typedef __attribute__((ext_vector_type(8))) short short8;
typedef __attribute__((ext_vector_type(4))) float floatx4;

__device__ __forceinline__ unsigned short f2bf(float f) {
    unsigned int u = __float_as_uint(f);
    u += 0x7fffu + ((u >> 16) & 1u);
    return (unsigned short)(u >> 16);
}
__device__ __forceinline__ float bf2f(unsigned short u) {
    return __uint_as_float(((unsigned int)u) << 16);
}

// ---------- prelude: fp32->bf16 cvt + weight transpose + dst histogram ----------
// Three independent read-only-input phases in ONE dispatch (R11, verified).
__global__ __launch_bounds__(512) void prelude_kernel(
    const float* __restrict__ x0, const float* __restrict__ Ws1,
    const float* __restrict__ Ws2, const int* __restrict__ dst,
    unsigned short* __restrict__ xbf, unsigned short* __restrict__ W1T,
    unsigned short* __restrict__ W2T, int* __restrict__ hist) {
    __shared__ int h[NBUK];
    int tid = threadIdx.x, bid = blockIdx.x;
    int gid = bid * 512 + tid;
    for (int idx = gid; idx < CVT_N; idx += NBLK * 512) {
        float4 f = ((const float4*)x0)[idx];
        ushort4 o;
        o.x = f2bf(f.x); o.y = f2bf(f.y); o.z = f2bf(f.z); o.w = f2bf(f.w);
        ((ushort4*)xbf)[idx] = o;
    }
    for (int idx = gid; idx < PREP_N; idx += NBLK * 512) {
        int l = idx >> 14, rem = idx & 16383;
        int k = rem >> 7, n = rem & 127;
        int o = (l << 14) + (n << 7) + k;
        W1T[o] = f2bf(Ws1[idx]);
        W2T[o] = f2bf(Ws2[idx]);
    }
    for (int i = tid; i < NBUK; i += 512) h[i] = 0;
    __syncthreads();
    {
        int base = bid * EPB;
        int end = base + EPB; if (end > NE) end = NE;
        for (int e = base + tid; e < end; e += 512) atomicAdd(&h[dst[e] >> BSH], 1);
    }
    __syncthreads();
    for (int i = tid; i < NBUK; i += 512) hist[i * NBLK + bid] = h[i];
}

// ---------- single-dispatch exclusive scan: decoupled aggregate lookback ------
// Flag+value packed in one u32 -> RELAXED poll, no acquire spin (R6/R7 lesson).
__global__ __launch_bounds__(512) void scan_lb_kernel(const int* __restrict__ in,
                                                      int* __restrict__ out,
                                                      unsigned int* __restrict__ tstat,
                                                      int n) {
    __shared__ int s[512];
    int b = blockIdx.x, tid = threadIdx.x;
    int i = b * 512 + tid;
    int v = (i < n) ? in[i] : 0;
    s[tid] = v;
    __syncthreads();
    for (int off = 1; off < 512; off <<= 1) {
        int u = (tid >= off) ? s[tid - off] : 0;
        __syncthreads();
        s[tid] += u;
        __syncthreads();
    }
    int incl = s[tid];
    int agg = s[511];
    if (tid == 0)
        __hip_atomic_store(&tstat[b], 0x80000000u | (unsigned int)agg,
                           __ATOMIC_RELAXED, __HIP_MEMORY_SCOPE_AGENT);
    unsigned int got = 0;
    if (tid < b) {
        unsigned int x = __hip_atomic_load(&tstat[tid], __ATOMIC_RELAXED,
                                           __HIP_MEMORY_SCOPE_AGENT);
        while (!(x & 0x80000000u)) {
            __builtin_amdgcn_s_sleep(1);
            x = __hip_atomic_load(&tstat[tid], __ATOMIC_RELAXED,
                                  __HIP_MEMORY_SCOPE_AGENT);
        }
        got = x & 0x7FFFFFFFu;
    }
    __syncthreads();
    s[tid] = (int)got;
    __syncthreads();
    for (int off = 256; off > 0; off >>= 1) {
        if (tid < off) s[tid] += s[tid + off];
        __syncthreads();
    }
    int carry = s[0];
    if (i < n) out[i] = carry + incl - v;  // exclusive prefix
}

// ---------- Pass 3: scatter edges into dst-bucketed ebuf, packed (src<<7)|(dst&127) ----
__global__ __launch_bounds__(512) void bscatter_kernel(const int* __restrict__ src,
                                                       const int* __restrict__ dst,
                                                       const int* __restrict__ bkoff,
                                                       int* __restrict__ ebuf) {
    __shared__ int h[NBUK];
    int tid = threadIdx.x;
    for (int i = tid; i < NBUK; i += 512) h[i] = 0;
    __syncthreads();
    int base = blockIdx.x * EPB;
#pragma unroll
    for (int it = 0; it < EPB / 512; it++) {
        int e = base + it * 512 + tid;
        if (e < NE) {
            int d = dst[e];
            int bu = d >> BSH;
            int p = atomicAdd(&h[bu], 1);
            ebuf[bkoff[bu * NBLK + blockIdx.x] + p] = (src[e] << BSH) | (d & BMSK);
        }
    }
}

// ---------- Pass 4: one block per 128-node bucket (R4-exact) ----------
__global__ __launch_bounds__(256) void bucket_csr_kernel(const int* __restrict__ ebuf,
                                                         const int* __restrict__ bkoff,
                                                         int* __restrict__ rowptr,
                                                         int* __restrict__ rowend,
                                                         int* __restrict__ col) {
    __shared__ int cnt[128], exc[128], ebase[128];
    int b = blockIdx.x, tid = threadIdx.x;
    int segstart = bkoff[b * NBLK];
    int segend = (b < NBUK - 1) ? bkoff[(b + 1) * NBLK] : NE;
    if (tid < 128) cnt[tid] = 0;
    __syncthreads();
    int evr[EPT];
    int rnk[EPT];
#pragma unroll
    for (int j = 0; j < EPT; j++) {
        int i = segstart + tid + j * 256;
        if (i < segend) {
            int ev = ebuf[i];
            evr[j] = ev;
            rnk[j] = atomicAdd(&cnt[ev & BMSK], 1);
        } else {
            evr[j] = -1;
        }
    }
    __syncthreads();
    int v = (tid < 128) ? cnt[tid] : 0;
    if (tid < 128) exc[tid] = v;
    __syncthreads();
    for (int off = 1; off < 128; off <<= 1) {
        int u = (tid < 128 && tid >= off) ? exc[tid - off] : 0;
        __syncthreads();
        if (tid < 128) exc[tid] += u;
        __syncthreads();
    }
    if (tid < 128) {
        int excl = exc[tid] - v;  // exclusive prefix
        ebase[tid] = segstart + excl;
        int node = (b << BSH) + tid;
        if (node < NN) {
            rowptr[node] = segstart + excl;
            rowend[node] = segstart + excl + v;
        }
    }
    __syncthreads();
#pragma unroll
    for (int j = 0; j < EPT; j++) {
        if (evr[j] >= 0) {
            int low = evr[j] & BMSK;
            col[ebase[low] + rnk[j]] = ((unsigned)evr[j]) >> BSH;
        }
    }
}

// ---------- aggregation: hpre[i] = x[i] + sum_{j in N(i)} x[j], bf16 in/out ----------
// R4-exact. Fabric-gather-bound at ~3.1 TB/s / ~154 MB: floor across 5
// structural variants (R1/R2/R3/R9/R10).
__global__ __launch_bounds__(256) void agg_kernel(const unsigned short* __restrict__ xbf,
                                                  const int* __restrict__ rowptr,
                                                  const int* __restrict__ rowend,
                                                  const int* __restrict__ col,
                                                  unsigned short* __restrict__ hpre) {
    int g = threadIdx.x >> 4;   // 16 node-groups per block
    int lane = threadIdx.x & 15;
    int node = blockIdx.x * 16 + g;  // NN = 3125*16 exactly
    const uint4* base = (const uint4*)xbf;
    float a[8];
    {
        uint4 v = base[node * 16 + lane];
        a[0] = __uint_as_float(v.x << 16); a[1] = __uint_as_float(v.x & 0xFFFF0000u);
        a[2] = __uint_as_float(v.y << 16); a[3] = __uint_as_float(v.y & 0xFFFF0000u);
        a[4] = __uint_as_float(v.z << 16); a[5] = __uint_as_float(v.z & 0xFFFF0000u);
        a[6] = __uint_as_float(v.w << 16); a[7] = __uint_as_float(v.w & 0xFFFF0000u);
    }
    int s = rowptr[node], e = rowend[node];
    int i = s;
    for (; i + 8 <= e; i += 8) {
        uint4 v0 = base[col[i] * 16 + lane];
        uint4 v1 = base[col[i + 1] * 16 + lane];
        uint4 v2 = base[col[i + 2] * 16 + lane];
        uint4 v3 = base[col[i + 3] * 16 + lane];
        uint4 v4 = base[col[i + 4] * 16 + lane];
        uint4 v5 = base[col[i + 5] * 16 + lane];
        uint4 v6 = base[col[i + 6] * 16 + lane];
        uint4 v7 = base[col[i + 7] * 16 + lane];
#define ACC(V)                                                            \
        a[0] += __uint_as_float(V.x << 16); a[1] += __uint_as_float(V.x & 0xFFFF0000u); \
        a[2] += __uint_as_float(V.y << 16); a[3] += __uint_as_float(V.y & 0xFFFF0000u); \
        a[4] += __uint_as_float(V.z << 16); a[5] += __uint_as_float(V.z & 0xFFFF0000u); \
        a[6] += __uint_as_float(V.w << 16); a[7] += __uint_as_float(V.w & 0xFFFF0000u)
        ACC(v0); ACC(v1); ACC(v2); ACC(v3); ACC(v4); ACC(v5); ACC(v6); ACC(v7);
    }
    for (; i < e; i++) {
        uint4 v = base[col[i] * 16 + lane];
        ACC(v);
    }
#undef ACC
    uint4 o;
    o.x = (unsigned int)f2bf(a[0]) | ((unsigned int)f2bf(a[1]) << 16);
    o.y = (unsigned int)f2bf(a[2]) | ((unsigned int)f2bf(a[3]) << 16);
    o.z = (unsigned int)f2bf(a[4]) | ((unsigned int)f2bf(a[5]) << 16);
    o.w = (unsigned int)f2bf(a[6]) | ((unsigned int)f2bf(a[7]) << 16);
    ((uint4*)hpre)[node * 16 + lane] = o;
}

// ---------- fused MLP: O = (relu(A@W1^T+b1))@W2^T + b2, one block per 128 rows ----
// R12: A-PREFETCH — the 16 xf global loads now issue BEFORE W1 staging, so
// their ~300-500cyc L3-hit latency hides under the stage+sync (T14/G15
// issue-early) instead of serializing with GEMM1. VGPR ~88->~150 (2 blocks/CU
// is LDS-capped at 64KB; 2 waves/SIMD allows 256 VGPR — no occupancy change).
// Everything else R4-exact: swapped-operand MFMA -> D[n][m], packed uint2
// stores, H in LDS, XOR-swizzle (G4/T2).
__global__ __launch_bounds__(256) void mlp_kernel(const unsigned short* __restrict__ A,
                                                  const unsigned short* __restrict__ W1,
                                                  const float* __restrict__ b1,
                                                  const unsigned short* __restrict__ W2,
                                                  const float* __restrict__ b2,
                                                  unsigned short* __restrict__ O) {
    __shared__ unsigned short Wl[128 * 128];  // 32 KB, holds W1 then W2
    __shared__ unsigned short Hl[128 * 128];  // 32 KB hidden tile
    int tid = threadIdx.x;
    int wg = tid >> 6;
    int lane = tid & 63;
    int quad = lane >> 4;
    int li = lane & 15;
    int mg = wg >> 1, ng = wg & 1;
    int rowb = blockIdx.x * 128;

    // ---- A-prefetch: all 16 fragment loads issued first ----
    short8 xf[4][4];
#pragma unroll
    for (int kk = 0; kk < 4; kk++) {
#pragma unroll
        for (int mi = 0; mi < 4; mi++) {
            int ar = rowb + mg * 64 + mi * 16 + li;
            xf[kk][mi] = (ar < NN)
                ? *(const short8*)(A + (size_t)ar * DD + kk * 32 + quad * 8)
                : (short8){0, 0, 0, 0, 0, 0, 0, 0};
        }
    }

    // ---- stage W1 ([n][k] bf16, swizzled) — A-load latency hides under this ----
    {
        const uint4* wgl = (const uint4*)W1;  // 2048 uint4
#pragma unroll
        for (int it = 0; it < 8; it++) {
            int idx = it * 256 + tid;
            int n = idx >> 4, kc = idx & 15;
            *(uint4*)&Wl[n * 128 + ((kc * 8) ^ ((n & 7) << 3))] = wgl[idx];
        }
    }
    __syncthreads();

    floatx4 acc[4][4];
#pragma unroll
    for (int tn = 0; tn < 4; tn++)
#pragma unroll
        for (int mi = 0; mi < 4; mi++) acc[tn][mi] = (floatx4){0.f, 0.f, 0.f, 0.f};

    // ---- GEMM1: D[n][m] = W1 . A^T ----
#pragma unroll
    for (int kk = 0; kk < 4; kk++) {
        int kc = kk * 32 + quad * 8;
#pragma unroll
        for (int tn = 0; tn < 4; tn++) {
            int wr = ng * 64 + tn * 16 + li;
            short8 wf = *(const short8*)&Wl[wr * 128 + (kc ^ ((wr & 7) << 3))];
#pragma unroll
            for (int mi = 0; mi < 4; mi++)
                acc[tn][mi] = __builtin_amdgcn_mfma_f32_16x16x32_bf16(wf, xf[kk][mi], acc[tn][mi], 0, 0, 0);
        }
    }

    // ---- epilogue 1: +b1, relu, bf16 -> Hl ----
#pragma unroll
    for (int tn = 0; tn < 4; tn++) {
        float4 bv = ((const float4*)b1)[ng * 16 + tn * 4 + quad];
#pragma unroll
        for (int mi = 0; mi < 4; mi++) {
            int hr = mg * 64 + mi * 16 + li;
            float v0 = fmaxf(acc[tn][mi][0] + bv.x, 0.f);
            float v1 = fmaxf(acc[tn][mi][1] + bv.y, 0.f);
            float v2 = fmaxf(acc[tn][mi][2] + bv.z, 0.f);
            float v3 = fmaxf(acc[tn][mi][3] + bv.w, 0.f);
            uint2 u;
            u.x = (unsigned int)f2bf(v0) | ((unsigned int)f2bf(v1) << 16);
            u.y = (unsigned int)f2bf(v2) | ((unsigned int)f2bf(v3) << 16);
            int c = (ng * 64 + tn * 16 + quad * 4) ^ ((hr & 7) << 3);
            *(uint2*)&Hl[hr * 128 + c] = u;
        }
    }
    __syncthreads();  // Wl(W1) reads done + Hl fully written

    // ---- stage W2 over Wl ----
    {
        const uint4* wgl = (const uint4*)W2;
#pragma unroll
        for (int it = 0; it < 8; it++) {
            int idx = it * 256 + tid;
            int n = idx >> 4, kc = idx & 15;
            *(uint4*)&Wl[n * 128 + ((kc * 8) ^ ((n & 7) << 3))] = wgl[idx];
        }
    }
    __syncthreads();

    // ---- GEMM2: D[n2][m] = W2 . H^T ----
#pragma unroll
    for (int tn = 0; tn < 4; tn++)
#pragma unroll
        for (int mi = 0; mi < 4; mi++) acc[tn][mi] = (floatx4){0.f, 0.f, 0.f, 0.f};

#pragma unroll
    for (int kk = 0; kk < 4; kk++) {
        int kc = kk * 32 + quad * 8;
        short8 hf[4];
#pragma unroll
        for (int mi = 0; mi < 4; mi++) {
            int hr = mg * 64 + mi * 16 + li;
            hf[mi] = *(const short8*)&Hl[hr * 128 + (kc ^ ((hr & 7) << 3))];
        }
#pragma unroll
        for (int tn = 0; tn < 4; tn++) {
            int wr = ng * 64 + tn * 16 + li;
            short8 wf = *(const short8*)&Wl[wr * 128 + (kc ^ ((wr & 7) << 3))];
#pragma unroll
            for (int mi = 0; mi < 4; mi++)
                acc[tn][mi] = __builtin_amdgcn_mfma_f32_16x16x32_bf16(wf, hf[mi], acc[tn][mi], 0, 0, 0);
        }
    }

    // ---- epilogue 2: +b2, bf16 -> global O (8B packed stores) ----
#pragma unroll
    for (int tn = 0; tn < 4; tn++) {
        float4 bv = ((const float4*)b2)[ng * 16 + tn * 4 + quad];
#pragma unroll
        for (int mi = 0; mi < 4; mi++) {
            int m = rowb + mg * 64 + mi * 16 + li;
            if (m < NN) {
                uint2 u;
                u.x = (unsigned int)f2bf(acc[tn][mi][0] + bv.x) |
                      ((unsigned int)f2bf(acc[tn][mi][1] + bv.y) << 16);
                u.y = (unsigned int)f2bf(acc[tn][mi][2] + bv.z) |
                      ((unsigned int)f2bf(acc[tn][mi][3] + bv.w) << 16);
                *(uint2*)&O[(size_t)m * DD + ng * 64 + tn * 16 + quad * 4] = u;
            }
        }
    }
}

// ---------- global add pool: batch sorted -> per-graph contiguous range ----------
// R12: 256 threads (2-row split) x 4 independent accumulators = 8 rows in
// flight (was 1) — pool was latency-bound at 1 load/thread in flight.
__global__ __launch_bounds__(256) void pool_kernel(const unsigned short* __restrict__ x,
                                                   const int* __restrict__ batch,
                                                   float* __restrict__ out) {
    int g = blockIdx.x;
    int lo = 0, hi = NN;
    while (lo < hi) { int mid = (lo + hi) >> 1; if (batch[mid] < g) lo = mid + 1; else hi = mid; }
    int s = lo;
    hi = NN;
    while (lo < hi) { int mid = (lo + hi) >> 1; if (batch[mid] < g + 1) lo = mid + 1; else hi = mid; }
    int e = lo;
    int d = threadIdx.x & 127;
    int half = threadIdx.x >> 7;  // 0 or 1: even/odd rows
    float a0 = 0.f, a1 = 0.f, a2 = 0.f, a3 = 0.f;
    int i = s + half;
    for (; i + 6 < e; i += 8) {
        unsigned short v0 = x[(size_t)i * DD + d];
        unsigned short v1 = x[(size_t)(i + 2) * DD + d];
        unsigned short v2 = x[(size_t)(i + 4) * DD + d];
        unsigned short v3 = x[(size_t)(i + 6) * DD + d];
        a0 += bf2f(v0); a1 += bf2f(v1); a2 += bf2f(v2); a3 += bf2f(v3);
    }
    for (; i < e; i += 2) a0 += bf2f(x[(size_t)i * DD + d]);
    float acc = (a0 + a1) + (a2 + a3);
    __shared__ float red[256];
    red[threadIdx.x] = acc;
    __syncthreads();
    if (threadIdx.x < 128) out[g * DD + d] = red[d] + red[128 + d];
}

extern "C" void kernel_launch(void* const* d_in, const int* in_sizes, int n_in,
                              void* d_out, int out_size, void* d_ws, size_t ws_size,
                              hipStream_t stream) {
    const float* x0 = (const float*)d_in[0];
    const int* edge = (const int*)d_in[1];
    const int* batch = (const int*)d_in[2];
    const float* Ws1 = (const float*)d_in[3];
    const float* bs1 = (const float*)d_in[4];
    const float* Ws2 = (const float*)d_in[5];
    const float* bs2 = (const float*)d_in[6];
    float* out = (float*)d_out;
    const int* src = edge;
    const int* dst = edge + NE;

    char* ws = (char*)d_ws;
    size_t off = 0;
    auto alloc = [&](size_t bytes) {
        void* p = ws + off;
        off += (bytes + 255) & ~(size_t)255;
        return p;
    };
    unsigned short* x0bf = (unsigned short*)alloc((size_t)NN * DD * 2);
    unsigned short* xA = (unsigned short*)alloc((size_t)NN * DD * 2);
    unsigned short* xB = (unsigned short*)alloc((size_t)NN * DD * 2);
    unsigned short* hpre = (unsigned short*)alloc((size_t)NN * DD * 2);
    int* col = (int*)alloc((size_t)NE * 4);
    int* ebuf = (int*)alloc((size_t)NE * 4);
    int* hist = (int*)alloc((size_t)HN * 4);
    int* bkoff = (int*)alloc((size_t)HN * 4);
    int* rowptr = (int*)alloc((size_t)(NN + 1) * 4);
    int* rowend = (int*)alloc((size_t)NN * 4);
    unsigned short* W1T = (unsigned short*)alloc((size_t)NL * DD * DD * 2);
    unsigned short* W2T = (unsigned short*)alloc((size_t)NL * DD * DD * 2);
    unsigned int* tstat = (unsigned int*)alloc(2048);  // HT lookback slots

    (void)hipMemsetAsync(tstat, 0, 2048, stream);
    prelude_kernel<<<NBLK, 512, 0, stream>>>(x0, Ws1, Ws2, dst, x0bf, W1T, W2T, hist);
    scan_lb_kernel<<<HT, 512, 0, stream>>>(hist, bkoff, tstat, HN);
    bscatter_kernel<<<NBLK, 512, 0, stream>>>(src, dst, bkoff, ebuf);
    bucket_csr_kernel<<<NBUK, 256, 0, stream>>>(ebuf, bkoff, rowptr, rowend, col);

    const unsigned short* xin = x0bf;
    unsigned short* bufs[2] = {xA, xB};
    const int mlp_grid = (NN + 127) / 128;  // 391
    for (int l = 0; l < NL; l++) {
        agg_kernel<<<NN / 16, 256, 0, stream>>>(xin, rowptr, rowend, col, hpre);
        unsigned short* xout = bufs[l & 1];
        mlp_kernel<<<mlp_grid, 256, 0, stream>>>(hpre, W1T + l * DD * DD, bs1 + l * DD,
                                                 W2T + l * DD * DD, bs2 + l * DD, xout);
        xin = xout;
    }
    pool_kernel<<<NG, 256, 0, stream>>>(xin, batch, out);
}

// Round 13
// 401.765 us; speedup vs baseline: 5.1104x; 1.0229x over previous
//
#include <hip/hip_runtime.h>

#define NN 50000
#define NE 1600000
#define DD 128
#define NL 4
#define NG 512
#define BSH 7       // bucket shift: 128 nodes per bucket
#define BMSK 127
#define NBUK 391    // ceil(50000/128)
#define NBLK 196    // edge blocks: ceil(NE/8192)
#define EPB 8192    // edges per block in bucket passes
#define HN (NBUK * NBLK)  // 76636
#define HT 150      // ceil(HN/512)
#define EPT 20      // bucket_csr: max edges per thread (seg mean 4096, max ~4350; cap 5120)
#define CVT_N (NN * DD / 4)    // 1600000 float4s
#define PREP_N (NL * DD * DD)  // 65536
#define GPRE 392    // prelude grid: 2x NBLK so cvt/prep fill the machine

typedef __attribute__((ext_vector_type(8))) short short8;
typedef __attribute__((ext_vector_type(4))) float floatx4;

__device__ __forceinline__ unsigned short f2bf(float f) {
    unsigned int u = __float_as_uint(f);
    u += 0x7fffu + ((u >> 16) & 1u);
    return (unsigned short)(u >> 16);
}
__device__ __forceinline__ float bf2f(unsigned short u) {
    return __uint_as_float(((unsigned int)u) << 16);
}

// async global->LDS DMA (16B/lane). LDS dest is wave-uniform base + lane*16.
#define GLOAD_LDS(g, l)                                               \
    __builtin_amdgcn_global_load_lds(                                 \
        (const __attribute__((address_space(1))) void*)(g),           \
        (__attribute__((address_space(3))) void*)(l), 16, 0, 0)

// ---------- prelude: fp32->bf16 cvt + weight transpose + dst histogram ----------
// R13: grid 392 (was 196): blocks >=196 skip the hist (layout pins NBLK=196)
// but stream cvt/prep -> 1.53 blocks/CU for the memory-bound phase (was 0.77,
// half the machine idle). Hist dst-reads prefetched before the atomic loop.
__global__ __launch_bounds__(512) void prelude_kernel(
    const float* __restrict__ x0, const float* __restrict__ Ws1,
    const float* __restrict__ Ws2, const int* __restrict__ dst,
    unsigned short* __restrict__ xbf, unsigned short* __restrict__ W1T,
    unsigned short* __restrict__ W2T, int* __restrict__ hist) {
    __shared__ int h[NBUK];
    int tid = threadIdx.x, bid = blockIdx.x;
    int gid = bid * 512 + tid;
    for (int idx = gid; idx < CVT_N; idx += GPRE * 512) {
        float4 f = ((const float4*)x0)[idx];
        ushort4 o;
        o.x = f2bf(f.x); o.y = f2bf(f.y); o.z = f2bf(f.z); o.w = f2bf(f.w);
        ((ushort4*)xbf)[idx] = o;
    }
    for (int idx = gid; idx < PREP_N; idx += GPRE * 512) {
        int l = idx >> 14, rem = idx & 16383;
        int k = rem >> 7, n = rem & 127;
        int o = (l << 14) + (n << 7) + k;
        W1T[o] = f2bf(Ws1[idx]);
        W2T[o] = f2bf(Ws2[idx]);
    }
    if (bid < NBLK) {
        for (int i = tid; i < NBUK; i += 512) h[i] = 0;
        __syncthreads();
        int base = bid * EPB;
        int darr[16];
#pragma unroll
        for (int it = 0; it < 16; it++) {
            int e = base + it * 512 + tid;
            darr[it] = (e < NE) ? dst[e] : -1;
        }
#pragma unroll
        for (int it = 0; it < 16; it++)
            if (darr[it] >= 0) atomicAdd(&h[darr[it] >> BSH], 1);
        __syncthreads();
        for (int i = tid; i < NBUK; i += 512) hist[i * NBLK + bid] = h[i];
    }
}

// ---------- single-dispatch exclusive scan: decoupled aggregate lookback ------
// Flag+value packed in one u32 -> RELAXED poll, no acquire spin (R6/R7 lesson).
__global__ __launch_bounds__(512) void scan_lb_kernel(const int* __restrict__ in,
                                                      int* __restrict__ out,
                                                      unsigned int* __restrict__ tstat,
                                                      int n) {
    __shared__ int s[512];
    int b = blockIdx.x, tid = threadIdx.x;
    int i = b * 512 + tid;
    int v = (i < n) ? in[i] : 0;
    s[tid] = v;
    __syncthreads();
    for (int off = 1; off < 512; off <<= 1) {
        int u = (tid >= off) ? s[tid - off] : 0;
        __syncthreads();
        s[tid] += u;
        __syncthreads();
    }
    int incl = s[tid];
    int agg = s[511];
    if (tid == 0)
        __hip_atomic_store(&tstat[b], 0x80000000u | (unsigned int)agg,
                           __ATOMIC_RELAXED, __HIP_MEMORY_SCOPE_AGENT);
    unsigned int got = 0;
    if (tid < b) {
        unsigned int x = __hip_atomic_load(&tstat[tid], __ATOMIC_RELAXED,
                                           __HIP_MEMORY_SCOPE_AGENT);
        while (!(x & 0x80000000u)) {
            __builtin_amdgcn_s_sleep(1);
            x = __hip_atomic_load(&tstat[tid], __ATOMIC_RELAXED,
                                  __HIP_MEMORY_SCOPE_AGENT);
        }
        got = x & 0x7FFFFFFFu;
    }
    __syncthreads();
    s[tid] = (int)got;
    __syncthreads();
    for (int off = 256; off > 0; off >>= 1) {
        if (tid < off) s[tid] += s[tid + off];
        __syncthreads();
    }
    int carry = s[0];
    if (i < n) out[i] = carry + incl - v;  // exclusive prefix
}

// ---------- Pass 3: scatter edges into dst-bucketed ebuf, packed (src<<7)|(dst&127) ----
// R13: (src,dst) batch prefetched into registers before the atomic chain —
// HBM latency hides under the LDS atomics instead of serializing per edge.
__global__ __launch_bounds__(512) void bscatter_kernel(const int* __restrict__ src,
                                                       const int* __restrict__ dst,
                                                       const int* __restrict__ bkoff,
                                                       int* __restrict__ ebuf) {
    __shared__ int h[NBUK];
    int tid = threadIdx.x;
    for (int i = tid; i < NBUK; i += 512) h[i] = 0;
    __syncthreads();
    int base = blockIdx.x * EPB;
    int sarr[16], darr[16];
#pragma unroll
    for (int it = 0; it < 16; it++) {
        int e = base + it * 512 + tid;
        if (e < NE) { sarr[it] = src[e]; darr[it] = dst[e]; }
        else { sarr[it] = 0; darr[it] = -1; }
    }
#pragma unroll
    for (int it = 0; it < 16; it++) {
        if (darr[it] >= 0) {
            int d = darr[it];
            int bu = d >> BSH;
            int p = atomicAdd(&h[bu], 1);
            ebuf[bkoff[bu * NBLK + blockIdx.x] + p] = (sarr[it] << BSH) | (d & BMSK);
        }
    }
}

// ---------- Pass 4: one block per 128-node bucket (R4-exact) ----------
__global__ __launch_bounds__(256) void bucket_csr_kernel(const int* __restrict__ ebuf,
                                                         const int* __restrict__ bkoff,
                                                         int* __restrict__ rowptr,
                                                         int* __restrict__ rowend,
                                                         int* __restrict__ col) {
    __shared__ int cnt[128], exc[128], ebase[128];
    int b = blockIdx.x, tid = threadIdx.x;
    int segstart = bkoff[b * NBLK];
    int segend = (b < NBUK - 1) ? bkoff[(b + 1) * NBLK] : NE;
    if (tid < 128) cnt[tid] = 0;
    __syncthreads();
    int evr[EPT];
    int rnk[EPT];
#pragma unroll
    for (int j = 0; j < EPT; j++) {
        int i = segstart + tid + j * 256;
        if (i < segend) {
            int ev = ebuf[i];
            evr[j] = ev;
            rnk[j] = atomicAdd(&cnt[ev & BMSK], 1);
        } else {
            evr[j] = -1;
        }
    }
    __syncthreads();
    int v = (tid < 128) ? cnt[tid] : 0;
    if (tid < 128) exc[tid] = v;
    __syncthreads();
    for (int off = 1; off < 128; off <<= 1) {
        int u = (tid < 128 && tid >= off) ? exc[tid - off] : 0;
        __syncthreads();
        if (tid < 128) exc[tid] += u;
        __syncthreads();
    }
    if (tid < 128) {
        int excl = exc[tid] - v;  // exclusive prefix
        ebase[tid] = segstart + excl;
        int node = (b << BSH) + tid;
        if (node < NN) {
            rowptr[node] = segstart + excl;
            rowend[node] = segstart + excl + v;
        }
    }
    __syncthreads();
#pragma unroll
    for (int j = 0; j < EPT; j++) {
        if (evr[j] >= 0) {
            int low = evr[j] & BMSK;
            col[ebase[low] + rnk[j]] = ((unsigned)evr[j]) >> BSH;
        }
    }
}

// ---------- aggregation: hpre[i] = x[i] + sum_{j in N(i)} x[j], bf16 in/out ----------
// R4-exact. Fabric-gather-bound at ~3.1 TB/s / ~154 MB: floor across 5
// structural variants (R1/R2/R3/R9/R10).
__global__ __launch_bounds__(256) void agg_kernel(const unsigned short* __restrict__ xbf,
                                                  const int* __restrict__ rowptr,
                                                  const int* __restrict__ rowend,
                                                  const int* __restrict__ col,
                                                  unsigned short* __restrict__ hpre) {
    int g = threadIdx.x >> 4;   // 16 node-groups per block
    int lane = threadIdx.x & 15;
    int node = blockIdx.x * 16 + g;  // NN = 3125*16 exactly
    const uint4* base = (const uint4*)xbf;
    float a[8];
    {
        uint4 v = base[node * 16 + lane];
        a[0] = __uint_as_float(v.x << 16); a[1] = __uint_as_float(v.x & 0xFFFF0000u);
        a[2] = __uint_as_float(v.y << 16); a[3] = __uint_as_float(v.y & 0xFFFF0000u);
        a[4] = __uint_as_float(v.z << 16); a[5] = __uint_as_float(v.z & 0xFFFF0000u);
        a[6] = __uint_as_float(v.w << 16); a[7] = __uint_as_float(v.w & 0xFFFF0000u);
    }
    int s = rowptr[node], e = rowend[node];
    int i = s;
    for (; i + 8 <= e; i += 8) {
        uint4 v0 = base[col[i] * 16 + lane];
        uint4 v1 = base[col[i + 1] * 16 + lane];
        uint4 v2 = base[col[i + 2] * 16 + lane];
        uint4 v3 = base[col[i + 3] * 16 + lane];
        uint4 v4 = base[col[i + 4] * 16 + lane];
        uint4 v5 = base[col[i + 5] * 16 + lane];
        uint4 v6 = base[col[i + 6] * 16 + lane];
        uint4 v7 = base[col[i + 7] * 16 + lane];
#define ACC(V)                                                            \
        a[0] += __uint_as_float(V.x << 16); a[1] += __uint_as_float(V.x & 0xFFFF0000u); \
        a[2] += __uint_as_float(V.y << 16); a[3] += __uint_as_float(V.y & 0xFFFF0000u); \
        a[4] += __uint_as_float(V.z << 16); a[5] += __uint_as_float(V.z & 0xFFFF0000u); \
        a[6] += __uint_as_float(V.w << 16); a[7] += __uint_as_float(V.w & 0xFFFF0000u)
        ACC(v0); ACC(v1); ACC(v2); ACC(v3); ACC(v4); ACC(v5); ACC(v6); ACC(v7);
    }
    for (; i < e; i++) {
        uint4 v = base[col[i] * 16 + lane];
        ACC(v);
    }
#undef ACC
    uint4 o;
    o.x = (unsigned int)f2bf(a[0]) | ((unsigned int)f2bf(a[1]) << 16);
    o.y = (unsigned int)f2bf(a[2]) | ((unsigned int)f2bf(a[3]) << 16);
    o.z = (unsigned int)f2bf(a[4]) | ((unsigned int)f2bf(a[5]) << 16);
    o.w = (unsigned int)f2bf(a[6]) | ((unsigned int)f2bf(a[7]) << 16);
    ((uint4*)hpre)[node * 16 + lane] = o;
}

// ---------- fused MLP: O = (relu(A@W1^T+b1))@W2^T + b2, one block per 128 rows ----
// R12: A-prefetch (verified −5 us/dispatch). R13: W staging via async
// global_load_lds — LINEAR LDS dest + PRE-SWIZZLED global src (m173 pattern;
// rule #21: both-sides-or-neither). Identity: (kc*8)^((n&7)<<3) = 8*(kc^(n&7)),
// so linear slot (n,kc) holds global chunk (n, kc^(n&7)) and the READ formula
// Wl[wr*128 + (kcs ^ ((wr&7)<<3))] is unchanged. Kills the VGPR round-trip.
__global__ __launch_bounds__(256) void mlp_kernel(const unsigned short* __restrict__ A,
                                                  const unsigned short* __restrict__ W1,
                                                  const float* __restrict__ b1,
                                                  const unsigned short* __restrict__ W2,
                                                  const float* __restrict__ b2,
                                                  unsigned short* __restrict__ O) {
    __shared__ unsigned short Wl[128 * 128];  // 32 KB, holds W1 then W2
    __shared__ unsigned short Hl[128 * 128];  // 32 KB hidden tile
    int tid = threadIdx.x;
    int wg = tid >> 6;
    int lane = tid & 63;
    int quad = lane >> 4;
    int li = lane & 15;
    int mg = wg >> 1, ng = wg & 1;
    int rowb = blockIdx.x * 128;

    // ---- A-prefetch: all 16 fragment loads issued first (R12, verified) ----
    short8 xf[4][4];
#pragma unroll
    for (int kk = 0; kk < 4; kk++) {
#pragma unroll
        for (int mi = 0; mi < 4; mi++) {
            int ar = rowb + mg * 64 + mi * 16 + li;
            xf[kk][mi] = (ar < NN)
                ? *(const short8*)(A + (size_t)ar * DD + kk * 32 + quad * 8)
                : (short8){0, 0, 0, 0, 0, 0, 0, 0};
        }
    }

    // ---- stage W1: async DMA, linear LDS, pre-swizzled source ----
    {
        const uint4* wgl = (const uint4*)W1;
        int wv = tid >> 6;
        int l = tid & 63;
#pragma unroll
        for (int it = 0; it < 8; it++) {
            int idx = it * 256 + wv * 64 + l;
            int n = idx >> 4, kc = idx & 15;
            GLOAD_LDS(wgl + n * 16 + (kc ^ (n & 7)), &Wl[(it * 256 + wv * 64) * 8]);
        }
    }
    __syncthreads();  // drains vmcnt: W1 staged AND A-prefetch landed

    floatx4 acc[4][4];
#pragma unroll
    for (int tn = 0; tn < 4; tn++)
#pragma unroll
        for (int mi = 0; mi < 4; mi++) acc[tn][mi] = (floatx4){0.f, 0.f, 0.f, 0.f};

    // ---- GEMM1: D[n][m] = W1 . A^T ----
#pragma unroll
    for (int kk = 0; kk < 4; kk++) {
        int kc = kk * 32 + quad * 8;
#pragma unroll
        for (int tn = 0; tn < 4; tn++) {
            int wr = ng * 64 + tn * 16 + li;
            short8 wf = *(const short8*)&Wl[wr * 128 + (kc ^ ((wr & 7) << 3))];
#pragma unroll
            for (int mi = 0; mi < 4; mi++)
                acc[tn][mi] = __builtin_amdgcn_mfma_f32_16x16x32_bf16(wf, xf[kk][mi], acc[tn][mi], 0, 0, 0);
        }
    }

    // ---- epilogue 1: +b1, relu, bf16 -> Hl ----
#pragma unroll
    for (int tn = 0; tn < 4; tn++) {
        float4 bv = ((const float4*)b1)[ng * 16 + tn * 4 + quad];
#pragma unroll
        for (int mi = 0; mi < 4; mi++) {
            int hr = mg * 64 + mi * 16 + li;
            float v0 = fmaxf(acc[tn][mi][0] + bv.x, 0.f);
            float v1 = fmaxf(acc[tn][mi][1] + bv.y, 0.f);
            float v2 = fmaxf(acc[tn][mi][2] + bv.z, 0.f);
            float v3 = fmaxf(acc[tn][mi][3] + bv.w, 0.f);
            uint2 u;
            u.x = (unsigned int)f2bf(v0) | ((unsigned int)f2bf(v1) << 16);
            u.y = (unsigned int)f2bf(v2) | ((unsigned int)f2bf(v3) << 16);
            int c = (ng * 64 + tn * 16 + quad * 4) ^ ((hr & 7) << 3);
            *(uint2*)&Hl[hr * 128 + c] = u;
        }
    }
    __syncthreads();  // Wl(W1) reads done + Hl fully written

    // ---- stage W2: async DMA, same pattern ----
    {
        const uint4* wgl = (const uint4*)W2;
        int wv = tid >> 6;
        int l = tid & 63;
#pragma unroll
        for (int it = 0; it < 8; it++) {
            int idx = it * 256 + wv * 64 + l;
            int n = idx >> 4, kc = idx & 15;
            GLOAD_LDS(wgl + n * 16 + (kc ^ (n & 7)), &Wl[(it * 256 + wv * 64) * 8]);
        }
    }
    __syncthreads();

    // ---- GEMM2: D[n2][m] = W2 . H^T ----
#pragma unroll
    for (int tn = 0; tn < 4; tn++)
#pragma unroll
        for (int mi = 0; mi < 4; mi++) acc[tn][mi] = (floatx4){0.f, 0.f, 0.f, 0.f};

#pragma unroll
    for (int kk = 0; kk < 4; kk++) {
        int kc = kk * 32 + quad * 8;
        short8 hf[4];
#pragma unroll
        for (int mi = 0; mi < 4; mi++) {
            int hr = mg * 64 + mi * 16 + li;
            hf[mi] = *(const short8*)&Hl[hr * 128 + (kc ^ ((hr & 7) << 3))];
        }
#pragma unroll
        for (int tn = 0; tn < 4; tn++) {
            int wr = ng * 64 + tn * 16 + li;
            short8 wf = *(const short8*)&Wl[wr * 128 + (kc ^ ((wr & 7) << 3))];
#pragma unroll
            for (int mi = 0; mi < 4; mi++)
                acc[tn][mi] = __builtin_amdgcn_mfma_f32_16x16x32_bf16(wf, hf[mi], acc[tn][mi], 0, 0, 0);
        }
    }

    // ---- epilogue 2: +b2, bf16 -> global O (8B packed stores) ----
#pragma unroll
    for (int tn = 0; tn < 4; tn++) {
        float4 bv = ((const float4*)b2)[ng * 16 + tn * 4 + quad];
#pragma unroll
        for (int mi = 0; mi < 4; mi++) {
            int m = rowb + mg * 64 + mi * 16 + li;
            if (m < NN) {
                uint2 u;
                u.x = (unsigned int)f2bf(acc[tn][mi][0] + bv.x) |
                      ((unsigned int)f2bf(acc[tn][mi][1] + bv.y) << 16);
                u.y = (unsigned int)f2bf(acc[tn][mi][2] + bv.z) |
                      ((unsigned int)f2bf(acc[tn][mi][3] + bv.w) << 16);
                *(uint2*)&O[(size_t)m * DD + ng * 64 + tn * 16 + quad * 4] = u;
            }
        }
    }
}

// ---------- global add pool: batch sorted -> per-graph contiguous range ----------
// R12 config (verified): 256 threads (2-row split) x 4 accumulators = 8 rows
// in flight.
__global__ __launch_bounds__(256) void pool_kernel(const unsigned short* __restrict__ x,
                                                   const int* __restrict__ batch,
                                                   float* __restrict__ out) {
    int g = blockIdx.x;
    int lo = 0, hi = NN;
    while (lo < hi) { int mid = (lo + hi) >> 1; if (batch[mid] < g) lo = mid + 1; else hi = mid; }
    int s = lo;
    hi = NN;
    while (lo < hi) { int mid = (lo + hi) >> 1; if (batch[mid] < g + 1) lo = mid + 1; else hi = mid; }
    int e = lo;
    int d = threadIdx.x & 127;
    int half = threadIdx.x >> 7;  // 0 or 1: even/odd rows
    float a0 = 0.f, a1 = 0.f, a2 = 0.f, a3 = 0.f;
    int i = s + half;
    for (; i + 6 < e; i += 8) {
        unsigned short v0 = x[(size_t)i * DD + d];
        unsigned short v1 = x[(size_t)(i + 2) * DD + d];
        unsigned short v2 = x[(size_t)(i + 4) * DD + d];
        unsigned short v3 = x[(size_t)(i + 6) * DD + d];
        a0 += bf2f(v0); a1 += bf2f(v1); a2 += bf2f(v2); a3 += bf2f(v3);
    }
    for (; i < e; i += 2) a0 += bf2f(x[(size_t)i * DD + d]);
    float acc = (a0 + a1) + (a2 + a3);
    __shared__ float red[256];
    red[threadIdx.x] = acc;
    __syncthreads();
    if (threadIdx.x < 128) out[g * DD + d] = red[d] + red[128 + d];
}

extern "C" void kernel_launch(void* const* d_in, const int* in_sizes, int n_in,
                              void* d_out, int out_size, void* d_ws, size_t ws_size,
                              hipStream_t stream) {
    const float* x0 = (const float*)d_in[0];
    const int* edge = (const int*)d_in[1];
    const int* batch = (const int*)d_in[2];
    const float* Ws1 = (const float*)d_in[3];
    const float* bs1 = (const float*)d_in[4];
    const float* Ws2 = (const float*)d_in[5];
    const float* bs2 = (const float*)d_in[6];
    float* out = (float*)d_out;
    const int* src = edge;
    const int* dst = edge + NE;

    char* ws = (char*)d_ws;
    size_t off = 0;
    auto alloc = [&](size_t bytes) {
        void* p = ws + off;
        off += (bytes + 255) & ~(size_t)255;
        return p;
    };
    unsigned short* x0bf = (unsigned short*)alloc((size_t)NN * DD * 2);
    unsigned short* xA = (unsigned short*)alloc((size_t)NN * DD * 2);
    unsigned short* xB = (unsigned short*)alloc((size_t)NN * DD * 2);
    unsigned short* hpre = (unsigned short*)alloc((size_t)NN * DD * 2);
    int* col = (int*)alloc((size_t)NE * 4);
    int* ebuf = (int*)alloc((size_t)NE * 4);
    int* hist = (int*)alloc((size_t)HN * 4);
    int* bkoff = (int*)alloc((size_t)HN * 4);
    int* rowptr = (int*)alloc((size_t)(NN + 1) * 4);
    int* rowend = (int*)alloc((size_t)NN * 4);
    unsigned short* W1T = (unsigned short*)alloc((size_t)NL * DD * DD * 2);
    unsigned short* W2T = (unsigned short*)alloc((size_t)NL * DD * DD * 2);
    unsigned int* tstat = (unsigned int*)alloc(2048);  // HT lookback slots

    (void)hipMemsetAsync(tstat, 0, 2048, stream);
    prelude_kernel<<<GPRE, 512, 0, stream>>>(x0, Ws1, Ws2, dst, x0bf, W1T, W2T, hist);
    scan_lb_kernel<<<HT, 512, 0, stream>>>(hist, bkoff, tstat, HN);
    bscatter_kernel<<<NBLK, 512, 0, stream>>>(src, dst, bkoff, ebuf);
    bucket_csr_kernel<<<NBUK, 256, 0, stream>>>(ebuf, bkoff, rowptr, rowend, col);

    const unsigned short* xin = x0bf;
    unsigned short* bufs[2] = {xA, xB};
    const int mlp_grid = (NN + 127) / 128;  // 391
    for (int l = 0; l < NL; l++) {
        agg_kernel<<<NN / 16, 256, 0, stream>>>(xin, rowptr, rowend, col, hpre);
        unsigned short* xout = bufs[l & 1];
        mlp_kernel<<<mlp_grid, 256, 0, stream>>>(hpre, W1T + l * DD * DD, bs1 + l * DD,
                                                 W2T + l * DD * DD, bs2 + l * DD, xout);
        xin = xout;
    }
    pool_kernel<<<NG, 256, 0, stream>>>(xin, batch, out);
}